// Round 2
// baseline (237.610 us; speedup 1.0000x reference)
//
#include <hip/hip_runtime.h>
#include <stdint.h>

typedef unsigned short u16;
typedef unsigned int   u32;
typedef __attribute__((ext_vector_type(8))) __bf16 bf8;   // 8 bf16 = 4 VGPR (MFMA A/B frag)
typedef __attribute__((ext_vector_type(4))) float  f4;    // MFMA C/D frag

#define NEG_INF (-__builtin_inff())

// sizes
#define BB 2
#define TT 2048
#define DD 1024
#define HH 16
#define HD 64
#define BT (BB*TT)   // 4096

__device__ __forceinline__ u16 f2bf(float f) {            // RNE fp32->bf16 (inputs finite)
  u32 u = __builtin_bit_cast(u32, f);
  u += 0x7FFFu + ((u >> 16) & 1u);
  return (u16)(u >> 16);
}

__device__ __forceinline__ void g2l16(const void* g, void* l) {
  // async global->LDS, 16B per lane; LDS dest = wave-uniform base + lane*16
  __builtin_amdgcn_global_load_lds((const __attribute__((address_space(1))) u32*)g,
                                   (__attribute__((address_space(3))) u32*)l, 16, 0, 0);
}

// ---------------- cast x: fp32 -> bf16, 8 elems/thread ----------------
__global__ void k_cast_x(const float* __restrict__ x, uint4* __restrict__ xb) {
  int i = blockIdx.x * 256 + threadIdx.x;                  // 524288 threads exactly
  const float4* xf = (const float4*)x;
  float4 a = xf[2*i], b = xf[2*i+1];
  uint4 o;
  o.x = (u32)f2bf(a.x) | ((u32)f2bf(a.y) << 16);
  o.y = (u32)f2bf(a.z) | ((u32)f2bf(a.w) << 16);
  o.z = (u32)f2bf(b.x) | ((u32)f2bf(b.y) << 16);
  o.w = (u32)f2bf(b.z) | ((u32)f2bf(b.w) << 16);
  xb[i] = o;
}

// ------------- transpose+cast weights: W[k][n] f32 -> WT[n][k] bf16 -------------
__global__ void k_twcast(const float* __restrict__ w0, const float* __restrict__ w1,
                         const float* __restrict__ w2, const float* __restrict__ w3,
                         u16* __restrict__ o0, u16* __restrict__ o1,
                         u16* __restrict__ o2, u16* __restrict__ o3) {
  const float* W; u16* O;
  switch (blockIdx.z) {
    case 0: W = w0; O = o0; break;
    case 1: W = w1; O = o1; break;
    case 2: W = w2; O = o2; break;
    default: W = w3; O = o3; break;
  }
  __shared__ __align__(16) u16 tile[64][80];
  int tid = threadIdx.x;
  int k0 = blockIdx.y * 64, n0 = blockIdx.x * 64;
#pragma unroll
  for (int it = 0; it < 4; ++it) {                         // load 64x64 f32, cast
    int c = it*256 + tid; int kr = c >> 4, ns = c & 15;
    float4 v = *(const float4*)(W + (size_t)(k0+kr)*DD + n0 + ns*4);
    u16* p = &tile[kr][ns*4];
    p[0] = f2bf(v.x); p[1] = f2bf(v.y); p[2] = f2bf(v.z); p[3] = f2bf(v.w);
  }
  __syncthreads();
#pragma unroll
  for (int it = 0; it < 2; ++it) {                         // store transposed bf16
    int c = it*256 + tid; int nr = c >> 3, ks = c & 7;
    u32 ww[4];
#pragma unroll
    for (int e = 0; e < 4; ++e) {
      u16 lo = tile[ks*8 + 2*e][nr], hi = tile[ks*8 + 2*e + 1][nr];
      ww[e] = (u32)lo | ((u32)hi << 16);
    }
    uint4 o; o.x = ww[0]; o.y = ww[1]; o.z = ww[2]; o.w = ww[3];
    *(uint4*)(O + (size_t)(n0+nr)*DD + k0 + ks*8) = o;
  }
}

// ---------------- fused QKV GEMM: X[4096,1024]bf16 @ {WqT,WkT,WvT} ----------------
// 128x128 tile, BK=32, 4 waves (2x2), 4x4 16x16x32 frags/wave.
// Q,K,V written as [b*H+h][t][64] bf16.
__global__ __launch_bounds__(256, 2) void k_qkv(const u16* __restrict__ xb,
    const u16* __restrict__ wqt, const u16* __restrict__ wkt, const u16* __restrict__ wvt,
    u16* __restrict__ qo, u16* __restrict__ ko, u16* __restrict__ vo) {
  __shared__ uint4 smem4[1024];                            // A 8KB | B 8KB
  char* smem = (char*)smem4;
  int tid = threadIdx.x, w = tid >> 6, l = tid & 63;
  int bid = blockIdx.y * 24 + blockIdx.x;                  // nwg=768, XCD swizzle (768%8==0)
  int wg = (bid & 7) * 96 + (bid >> 3);
  int nb = wg % 24, mb = wg / 24;
  const u16* Bt = (nb < 8) ? wqt : (nb < 16 ? wkt : wvt);
  int nbl = nb & 7;
  int wm = w >> 1, wn = w & 1;
  f4 z = {0.f, 0.f, 0.f, 0.f};
  f4 acc[4][4];
#pragma unroll
  for (int i = 0; i < 4; ++i)
#pragma unroll
    for (int j = 0; j < 4; ++j) acc[i][j] = z;

  for (int kt = 0; kt < 32; ++kt) {
    int kk = kt * 32;
    __syncthreads();
#pragma unroll
    for (int i = 0; i < 2; ++i) {                          // stage A (swizzled source)
      int c = i*256 + tid; int row = c >> 2, u = c & 3, s = u ^ ((row >> 1) & 3);
      g2l16(xb + (size_t)(mb*128 + row)*DD + kk + s*8, smem + (i*256 + w*64)*16);
    }
#pragma unroll
    for (int i = 0; i < 2; ++i) {                          // stage B
      int c = i*256 + tid; int row = c >> 2, u = c & 3, s = u ^ ((row >> 1) & 3);
      g2l16(Bt + (size_t)(nbl*128 + row)*DD + kk + s*8, smem + 8192 + (i*256 + w*64)*16);
    }
    __syncthreads();
    bf8 af[4], bfr[4];
#pragma unroll
    for (int mf = 0; mf < 4; ++mf) {
      int row = wm*64 + mf*16 + (l & 15);
      int s = (l >> 4) ^ ((row >> 1) & 3);
      af[mf] = *(const bf8*)(smem + row*64 + s*16);
    }
#pragma unroll
    for (int nf = 0; nf < 4; ++nf) {
      int row = wn*64 + nf*16 + (l & 15);
      int s = (l >> 4) ^ ((row >> 1) & 3);
      bfr[nf] = *(const bf8*)(smem + 8192 + row*64 + s*16);
    }
#pragma unroll
    for (int mf = 0; mf < 4; ++mf)
#pragma unroll
      for (int nf = 0; nf < 4; ++nf)
        acc[mf][nf] = __builtin_amdgcn_mfma_f32_16x16x32_bf16(af[mf], bfr[nf], acc[mf][nf], 0, 0, 0);
  }
  u16* Out = (nb < 8) ? qo : (nb < 16 ? ko : vo);
#pragma unroll
  for (int mf = 0; mf < 4; ++mf) {
    int m0 = mb*128 + wm*64 + mf*16 + (l >> 4)*4;
    int b = m0 >> 11;                                      // m0 mult of 4, T mult of 4 -> same b
#pragma unroll
    for (int nf = 0; nf < 4; ++nf) {
      int nn = nbl*128 + wn*64 + nf*16 + (l & 15);
      int h = nn >> 6, d = nn & 63;
#pragma unroll
      for (int r = 0; r < 4; ++r) {
        int t = (m0 + r) & 2047;
        Out[(size_t)((b*HH + h)*TT + t)*HD + d] = f2bf(acc[mf][nf][r]);
      }
    }
  }
}

// ---------------- V transpose per head: [bh][t][64] -> [bh][64][t] ----------------
__global__ void k_vt(const u16* __restrict__ v, u16* __restrict__ vt) {
  __shared__ __align__(16) u16 tile[64][80];
  int tid = threadIdx.x;
  int bh = blockIdx.y, t0 = blockIdx.x * 64;
#pragma unroll
  for (int it = 0; it < 2; ++it) {
    int c = it*256 + tid; int tr = c >> 3, ds_ = c & 7;
    uint4 val = *(const uint4*)(v + (size_t)(bh*TT + t0 + tr)*HD + ds_*8);
    *(uint4*)&tile[tr][ds_*8] = val;
  }
  __syncthreads();
#pragma unroll
  for (int it = 0; it < 2; ++it) {
    int c = it*256 + tid; int dr = c >> 3, ts = c & 7;
    u32 ww[4];
#pragma unroll
    for (int e = 0; e < 4; ++e) {
      u16 lo = tile[ts*8 + 2*e][dr], hi = tile[ts*8 + 2*e + 1][dr];
      ww[e] = (u32)lo | ((u32)hi << 16);
    }
    uint4 o; o.x = ww[0]; o.y = ww[1]; o.z = ww[2]; o.w = ww[3];
    *(uint4*)(vt + (size_t)(bh*HD + dr)*TT + t0 + ts*8) = o;
  }
}

// ---------------- flash attention, causal ----------------
// block: 4 waves, QBLK=64 (16 q-rows/wave), KBLK=128, online softmax.
// LDS: K-tile [128][64] swz8 | VT-tile [64][128] swz16 | P per-wave [16][136]
__global__ __launch_bounds__(256, 2) void k_attn(const u16* __restrict__ q,
    const u16* __restrict__ kk, const u16* __restrict__ vt, u16* __restrict__ ctx) {
  __shared__ __align__(16) char smem[50176];
  int tid = threadIdx.x, w = tid >> 6, l = tid & 63;
  int bh = blockIdx.y, q0 = blockIdx.x * 64;
  int qw = q0 + w * 16;
  const u16* qbase = q + (size_t)(bh*TT + qw + (l & 15))*HD + (l >> 4)*8;
  bf8 qf0 = *(const bf8*)(qbase);
  bf8 qf1 = *(const bf8*)(qbase + 32);
  float mreg[4] = {NEG_INF, NEG_INF, NEG_INF, NEG_INF};
  float lreg[4] = {0.f, 0.f, 0.f, 0.f};
  f4 z = {0.f, 0.f, 0.f, 0.f};
  f4 acc[4]; acc[0] = z; acc[1] = z; acc[2] = z; acc[3] = z;
  char* Pb = smem + 32768 + w * 4352;
  int ktmax = (q0 + 63) >> 7;
  for (int kt = 0; kt <= ktmax; ++kt) {
    __syncthreads();
#pragma unroll
    for (int i = 0; i < 4; ++i) {                          // stage K (swizzled)
      int c = i*256 + tid; int row = c >> 3, u = c & 7;
      g2l16(kk + (size_t)(bh*TT + kt*128 + row)*HD + (u ^ (row & 7))*8,
            smem + (i*256 + w*64)*16);
    }
#pragma unroll
    for (int i = 0; i < 4; ++i) {                          // stage VT (swizzled)
      int c = i*256 + tid; int row = c >> 4, u = c & 15;
      g2l16(vt + (size_t)(bh*HD + row)*TT + kt*128 + (u ^ (row & 15))*8,
            smem + 16384 + (i*256 + w*64)*16);
    }
    __syncthreads();
    f4 sv[8];
#pragma unroll
    for (int jf = 0; jf < 8; ++jf) {                       // S = Q K^T (16x16 frags)
      f4 s = z;
      int row = jf*16 + (l & 15);
      int s0 = (l >> 4) ^ (row & 7);
      int s1 = ((l >> 4) + 4) ^ (row & 7);
      bf8 b0 = *(const bf8*)(smem + row*128 + s0*16);
      bf8 b1 = *(const bf8*)(smem + row*128 + s1*16);
      s = __builtin_amdgcn_mfma_f32_16x16x32_bf16(qf0, b0, s, 0, 0, 0);
      s = __builtin_amdgcn_mfma_f32_16x16x32_bf16(qf1, b1, s, 0, 0, 0);
      sv[jf] = s;
    }
    // FIX (R1): per-wave skip condition. Old code compared against q0+63 and
    // skipped masking on the diagonal tile for q0 % 128 == 64 blocks, leaking
    // future keys into waves 0..2 (non-causal attention on half the rows).
    bool need_mask = (kt*128 + 127) > qw;
#pragma unroll
    for (int jf = 0; jf < 8; ++jf) {                       // scale + causal mask
      int key = kt*128 + jf*16 + (l & 15);
#pragma unroll
      for (int r = 0; r < 4; ++r) {
        float val = sv[jf][r] * 0.125f;
        if (need_mask) {
          int qrow = qw + (l >> 4)*4 + r;
          if (key > qrow) val = NEG_INF;
        }
        sv[jf][r] = val;
      }
    }
    float alpha[4];
#pragma unroll
    for (int r = 0; r < 4; ++r) {                          // row max (8 frags + 16 lanes)
      float mx = sv[0][r];
#pragma unroll
      for (int jf = 1; jf < 8; ++jf) mx = fmaxf(mx, sv[jf][r]);
#pragma unroll
      for (int d = 1; d < 16; d <<= 1) mx = fmaxf(mx, __shfl_xor(mx, d, 64));
      float mnew = fmaxf(mreg[r], mx);
      alpha[r] = __expf(mreg[r] - mnew);
      mreg[r] = mnew;
    }
    float rs[4] = {0.f, 0.f, 0.f, 0.f};
#pragma unroll
    for (int jf = 0; jf < 8; ++jf) {                       // P = exp(S-m) -> LDS (bf16)
      int col = jf*16 + (l & 15);
#pragma unroll
      for (int r = 0; r < 4; ++r) {
        float p = __expf(sv[jf][r] - mreg[r]);
        rs[r] += p;
        *(u16*)(Pb + ((l >> 4)*4 + r)*272 + col*2) = f2bf(p);
      }
    }
#pragma unroll
    for (int r = 0; r < 4; ++r) {
      float t_ = rs[r];
#pragma unroll
      for (int d = 1; d < 16; d <<= 1) t_ += __shfl_xor(t_, d, 64);
      lreg[r] = lreg[r]*alpha[r] + t_;
    }
#pragma unroll
    for (int df = 0; df < 4; ++df) {                       // rescale O accumulator
      f4 a = acc[df];
      a[0] *= alpha[0]; a[1] *= alpha[1]; a[2] *= alpha[2]; a[3] *= alpha[3];
      acc[df] = a;
    }
#pragma unroll
    for (int ks = 0; ks < 4; ++ks) {                       // O += P V
      bf8 pf = *(const bf8*)(Pb + (l & 15)*272 + ks*64 + (l >> 4)*16);
#pragma unroll
      for (int df = 0; df < 4; ++df) {
        int row = df*16 + (l & 15);
        int sl = (ks*4 + (l >> 4)) ^ (row & 15);
        bf8 vf = *(const bf8*)(smem + 16384 + row*256 + sl*16);
        acc[df] = __builtin_amdgcn_mfma_f32_16x16x32_bf16(pf, vf, acc[df], 0, 0, 0);
      }
    }
  }
  int b = bh >> 4, h = bh & 15;
#pragma unroll
  for (int r = 0; r < 4; ++r) {
    float inv = 1.0f / lreg[r];
    int t = q0 + w*16 + (l >> 4)*4 + r;
    u16* dst = ctx + (size_t)(b*TT + t)*DD + h*HD;
#pragma unroll
    for (int df = 0; df < 4; ++df)
      dst[df*16 + (l & 15)] = f2bf(acc[df][r] * inv);
  }
}

// ---------------- output GEMM: ctx[4096,1024]bf16 @ WoT + bo -> fp32 ----------------
__global__ __launch_bounds__(256, 2) void k_out(const u16* __restrict__ ctx,
    const u16* __restrict__ wot, const float* __restrict__ bo, float* __restrict__ out) {
  __shared__ uint4 smem4[1024];
  char* smem = (char*)smem4;
  int tid = threadIdx.x, w = tid >> 6, l = tid & 63;
  int bid = blockIdx.y * 8 + blockIdx.x;                   // nwg=256
  int wg = (bid & 7) * 32 + (bid >> 3);
  int nb = wg % 8, mb = wg / 8;
  int wm = w >> 1, wn = w & 1;
  f4 z = {0.f, 0.f, 0.f, 0.f};
  f4 acc[4][4];
#pragma unroll
  for (int i = 0; i < 4; ++i)
#pragma unroll
    for (int j = 0; j < 4; ++j) acc[i][j] = z;

  for (int kt = 0; kt < 32; ++kt) {
    int kkk = kt * 32;
    __syncthreads();
#pragma unroll
    for (int i = 0; i < 2; ++i) {
      int c = i*256 + tid; int row = c >> 2, u = c & 3, s = u ^ ((row >> 1) & 3);
      g2l16(ctx + (size_t)(mb*128 + row)*DD + kkk + s*8, smem + (i*256 + w*64)*16);
    }
#pragma unroll
    for (int i = 0; i < 2; ++i) {
      int c = i*256 + tid; int row = c >> 2, u = c & 3, s = u ^ ((row >> 1) & 3);
      g2l16(wot + (size_t)(nb*128 + row)*DD + kkk + s*8, smem + 8192 + (i*256 + w*64)*16);
    }
    __syncthreads();
    bf8 af[4], bfr[4];
#pragma unroll
    for (int mf = 0; mf < 4; ++mf) {
      int row = wm*64 + mf*16 + (l & 15);
      int s = (l >> 4) ^ ((row >> 1) & 3);
      af[mf] = *(const bf8*)(smem + row*64 + s*16);
    }
#pragma unroll
    for (int nf = 0; nf < 4; ++nf) {
      int row = wn*64 + nf*16 + (l & 15);
      int s = (l >> 4) ^ ((row >> 1) & 3);
      bfr[nf] = *(const bf8*)(smem + 8192 + row*64 + s*16);
    }
#pragma unroll
    for (int mf = 0; mf < 4; ++mf)
#pragma unroll
      for (int nf = 0; nf < 4; ++nf)
        acc[mf][nf] = __builtin_amdgcn_mfma_f32_16x16x32_bf16(af[mf], bfr[nf], acc[mf][nf], 0, 0, 0);
  }
#pragma unroll
  for (int nf = 0; nf < 4; ++nf) {
    int n = nb*128 + wn*64 + nf*16 + (l & 15);
    float bias = bo[n];
#pragma unroll
    for (int mf = 0; mf < 4; ++mf) {
      int m0 = mb*128 + wm*64 + mf*16 + (l >> 4)*4;
#pragma unroll
      for (int r = 0; r < 4; ++r)
        out[(size_t)(m0 + r)*DD + n] = acc[mf][nf][r] + bias;
    }
  }
}

extern "C" void kernel_launch(void* const* d_in, const int* in_sizes, int n_in,
                              void* d_out, int out_size, void* d_ws, size_t ws_size,
                              hipStream_t stream) {
  const float* x  = (const float*)d_in[0];
  const float* Wq = (const float*)d_in[1];
  const float* Wk = (const float*)d_in[2];
  const float* Wv = (const float*)d_in[3];
  const float* Wo = (const float*)d_in[4];
  const float* bo = (const float*)d_in[5];
  float* out = (float*)d_out;
  char* ws = (char*)d_ws;

  u16* xb  = (u16*)(ws);                                   // 8 MB bf16 x
  u16* wqt = (u16*)(ws + 8388608);                         // 2 MB each, transposed bf16
  u16* wkt = (u16*)(ws + 10485760);
  u16* wvt = (u16*)(ws + 12582912);
  u16* wot = (u16*)(ws + 14680064);
  u16* qb_ = (u16*)(ws + 16777216);                        // 8 MB [bh][t][64]
  u16* kb_ = (u16*)(ws + 25165824);
  u16* vb_ = (u16*)(ws + 33554432);
  u16* vtb = (u16*)(ws + 41943040);                        // 8 MB [bh][64][t]
  u16* cxb = (u16*)(ws + 50331648);                        // 8 MB [b*t][1024]

  k_cast_x<<<dim3(2048), dim3(256), 0, stream>>>(x, (uint4*)xb);
  k_twcast<<<dim3(16, 16, 4), dim3(256), 0, stream>>>(Wq, Wk, Wv, Wo, wqt, wkt, wvt, wot);
  k_qkv<<<dim3(24, 32), dim3(256), 0, stream>>>(xb, wqt, wkt, wvt, qb_, kb_, vb_);
  k_vt<<<dim3(32, 32), dim3(256), 0, stream>>>(vb_, vtb);
  k_attn<<<dim3(32, 32), dim3(256), 0, stream>>>(qb_, kb_, vtb, cxb);
  k_out<<<dim3(8, 32), dim3(256), 0, stream>>>(cxb, wot, bo, out);
}

// Round 3
// 199.973 us; speedup vs baseline: 1.1882x; 1.1882x over previous
//
#include <hip/hip_runtime.h>
#include <stdint.h>

typedef unsigned short u16;
typedef unsigned int   u32;
typedef __attribute__((ext_vector_type(8))) __bf16 bf8;   // 8 bf16 = 4 VGPR (MFMA A/B frag)
typedef __attribute__((ext_vector_type(4))) float  f4;    // MFMA C/D frag

#define NEG_INF (-__builtin_inff())

// sizes
#define BB 2
#define TT 2048
#define DD 1024
#define HH 16
#define HD 64
#define BT (BB*TT)   // 4096

#define SBAR() __builtin_amdgcn_s_barrier()
#define VMCNT4() asm volatile("s_waitcnt vmcnt(4)" ::: "memory")
#define VMCNT0() asm volatile("s_waitcnt vmcnt(0)" ::: "memory")
#define LGKMCNT0() asm volatile("s_waitcnt lgkmcnt(0)" ::: "memory")

__device__ __forceinline__ u16 f2bf(float f) {            // RNE fp32->bf16 (inputs finite)
  u32 u = __builtin_bit_cast(u32, f);
  u += 0x7FFFu + ((u >> 16) & 1u);
  return (u16)(u >> 16);
}

__device__ __forceinline__ void g2l16(const void* g, void* l) {
  // async global->LDS, 16B per lane; LDS dest = wave-uniform base + lane*16
  __builtin_amdgcn_global_load_lds((const __attribute__((address_space(1))) u32*)g,
                                   (__attribute__((address_space(3))) u32*)l, 16, 0, 0);
}

// ---------------- cast x: fp32 -> bf16, 8 elems/thread ----------------
__global__ void k_cast_x(const float* __restrict__ x, uint4* __restrict__ xb) {
  int i = blockIdx.x * 256 + threadIdx.x;                  // 524288 threads exactly
  const float4* xf = (const float4*)x;
  float4 a = xf[2*i], b = xf[2*i+1];
  uint4 o;
  o.x = (u32)f2bf(a.x) | ((u32)f2bf(a.y) << 16);
  o.y = (u32)f2bf(a.z) | ((u32)f2bf(a.w) << 16);
  o.z = (u32)f2bf(b.x) | ((u32)f2bf(b.y) << 16);
  o.w = (u32)f2bf(b.z) | ((u32)f2bf(b.w) << 16);
  xb[i] = o;
}

// ------------- transpose+cast weights: W[k][n] f32 -> WT[n][k] bf16 -------------
__global__ void k_twcast(const float* __restrict__ w0, const float* __restrict__ w1,
                         const float* __restrict__ w2, const float* __restrict__ w3,
                         u16* __restrict__ o0, u16* __restrict__ o1,
                         u16* __restrict__ o2, u16* __restrict__ o3) {
  const float* W; u16* O;
  switch (blockIdx.z) {
    case 0: W = w0; O = o0; break;
    case 1: W = w1; O = o1; break;
    case 2: W = w2; O = o2; break;
    default: W = w3; O = o3; break;
  }
  __shared__ __align__(16) u16 tile[64][80];
  int tid = threadIdx.x;
  int k0 = blockIdx.y * 64, n0 = blockIdx.x * 64;
#pragma unroll
  for (int it = 0; it < 4; ++it) {                         // load 64x64 f32, cast
    int c = it*256 + tid; int kr = c >> 4, ns = c & 15;
    float4 v = *(const float4*)(W + (size_t)(k0+kr)*DD + n0 + ns*4);
    u16* p = &tile[kr][ns*4];
    p[0] = f2bf(v.x); p[1] = f2bf(v.y); p[2] = f2bf(v.z); p[3] = f2bf(v.w);
  }
  __syncthreads();
#pragma unroll
  for (int it = 0; it < 2; ++it) {                         // store transposed bf16
    int c = it*256 + tid; int nr = c >> 3, ks = c & 7;
    u32 ww[4];
#pragma unroll
    for (int e = 0; e < 4; ++e) {
      u16 lo = tile[ks*8 + 2*e][nr], hi = tile[ks*8 + 2*e + 1][nr];
      ww[e] = (u32)lo | ((u32)hi << 16);
    }
    uint4 o; o.x = ww[0]; o.y = ww[1]; o.z = ww[2]; o.w = ww[3];
    *(uint4*)(O + (size_t)(n0+nr)*DD + k0 + ks*8) = o;
  }
}

// ---------------- fused QKV GEMM: X[4096,1024]bf16 @ {WqT,WkT,WvT} ----------------
__global__ __launch_bounds__(256, 2) void k_qkv(const u16* __restrict__ xb,
    const u16* __restrict__ wqt, const u16* __restrict__ wkt, const u16* __restrict__ wvt,
    u16* __restrict__ qo, u16* __restrict__ ko, u16* __restrict__ vo) {
  __shared__ uint4 smem4[1024];                            // A 8KB | B 8KB
  char* smem = (char*)smem4;
  int tid = threadIdx.x, w = tid >> 6, l = tid & 63;
  int bid = blockIdx.y * 24 + blockIdx.x;                  // nwg=768, XCD swizzle (768%8==0)
  int wg = (bid & 7) * 96 + (bid >> 3);
  int nb = wg % 24, mb = wg / 24;
  const u16* Bt = (nb < 8) ? wqt : (nb < 16 ? wkt : wvt);
  int nbl = nb & 7;
  int wm = w >> 1, wn = w & 1;
  f4 z = {0.f, 0.f, 0.f, 0.f};
  f4 acc[4][4];
#pragma unroll
  for (int i = 0; i < 4; ++i)
#pragma unroll
    for (int j = 0; j < 4; ++j) acc[i][j] = z;

  for (int kt = 0; kt < 32; ++kt) {
    int kk = kt * 32;
    __syncthreads();
#pragma unroll
    for (int i = 0; i < 2; ++i) {                          // stage A (swizzled source)
      int c = i*256 + tid; int row = c >> 2, u = c & 3, s = u ^ ((row >> 1) & 3);
      g2l16(xb + (size_t)(mb*128 + row)*DD + kk + s*8, smem + (i*256 + w*64)*16);
    }
#pragma unroll
    for (int i = 0; i < 2; ++i) {                          // stage B
      int c = i*256 + tid; int row = c >> 2, u = c & 3, s = u ^ ((row >> 1) & 3);
      g2l16(Bt + (size_t)(nbl*128 + row)*DD + kk + s*8, smem + 8192 + (i*256 + w*64)*16);
    }
    __syncthreads();
    bf8 af[4], bfr[4];
#pragma unroll
    for (int mf = 0; mf < 4; ++mf) {
      int row = wm*64 + mf*16 + (l & 15);
      int s = (l >> 4) ^ ((row >> 1) & 3);
      af[mf] = *(const bf8*)(smem + row*64 + s*16);
    }
#pragma unroll
    for (int nf = 0; nf < 4; ++nf) {
      int row = wn*64 + nf*16 + (l & 15);
      int s = (l >> 4) ^ ((row >> 1) & 3);
      bfr[nf] = *(const bf8*)(smem + 8192 + row*64 + s*16);
    }
#pragma unroll
    for (int mf = 0; mf < 4; ++mf)
#pragma unroll
      for (int nf = 0; nf < 4; ++nf)
        acc[mf][nf] = __builtin_amdgcn_mfma_f32_16x16x32_bf16(af[mf], bfr[nf], acc[mf][nf], 0, 0, 0);
  }
  u16* Out = (nb < 8) ? qo : (nb < 16 ? ko : vo);
#pragma unroll
  for (int mf = 0; mf < 4; ++mf) {
    int m0 = mb*128 + wm*64 + mf*16 + (l >> 4)*4;
    int b = m0 >> 11;                                      // m0 mult of 4, T mult of 4 -> same b
#pragma unroll
    for (int nf = 0; nf < 4; ++nf) {
      int nn = nbl*128 + wn*64 + nf*16 + (l & 15);
      int h = nn >> 6, d = nn & 63;
#pragma unroll
      for (int r = 0; r < 4; ++r) {
        int t = (m0 + r) & 2047;
        Out[(size_t)((b*HH + h)*TT + t)*HD + d] = f2bf(acc[mf][nf][r]);
      }
    }
  }
}

// ---------------- V transpose per head: [bh][t][64] -> [bh][64][t] ----------------
__global__ void k_vt(const u16* __restrict__ v, u16* __restrict__ vt) {
  __shared__ __align__(16) u16 tile[64][80];
  int tid = threadIdx.x;
  int bh = blockIdx.y, t0 = blockIdx.x * 64;
#pragma unroll
  for (int it = 0; it < 2; ++it) {
    int c = it*256 + tid; int tr = c >> 3, ds_ = c & 7;
    uint4 val = *(const uint4*)(v + (size_t)(bh*TT + t0 + tr)*HD + ds_*8);
    *(uint4*)&tile[tr][ds_*8] = val;
  }
  __syncthreads();
#pragma unroll
  for (int it = 0; it < 2; ++it) {
    int c = it*256 + tid; int dr = c >> 3, ts = c & 7;
    u32 ww[4];
#pragma unroll
    for (int e = 0; e < 4; ++e) {
      u16 lo = tile[ts*8 + 2*e][dr], hi = tile[ts*8 + 2*e + 1][dr];
      ww[e] = (u32)lo | ((u32)hi << 16);
    }
    uint4 o; o.x = ww[0]; o.y = ww[1]; o.z = ww[2]; o.w = ww[3];
    *(uint4*)(vt + (size_t)(bh*HD + dr)*TT + t0 + ts*8) = o;
  }
}

// ---------------- flash attention, causal; pair-balanced + 2-phase prefetch ----------------
// Block handles q-tiles (ip, 31-ip) of one bh -> uniform 17 K-tile iters/block.
// Grid 512 flat; bh grouped 4-per-XCD (K/V 2MB L2-resident per XCD).
// Per iter: vmcnt(4) K-visible | QK^T | lgkm+bar | stageK(t+1) | softmax |
//           vmcnt(4) V-visible | PV | lgkm+bar | stageV(t+1)
__global__ __launch_bounds__(256, 2) void k_attn(const u16* __restrict__ q,
    const u16* __restrict__ kk, const u16* __restrict__ vt, u16* __restrict__ ctx) {
  __shared__ __align__(16) char smem[50176];               // K 16K | V 16K | P 4x4352
  int tid = threadIdx.x, w = tid >> 6, l = tid & 63;
  int fid = blockIdx.x;
  int xcd = fid & 7, j = fid >> 3;
  int bh  = xcd * 4 + (j & 3);                             // 4 bh per XCD
  int ip  = j >> 2;                                        // 0..15 pair index
  char* Pb = smem + 32768 + w * 4352;
  int b = bh >> 4, h = bh & 15;

  auto stageK = [&](int t) {
#pragma unroll
    for (int i = 0; i < 4; ++i) {
      int c = i*256 + tid; int row = c >> 3, u = c & 7;
      g2l16(kk + (size_t)(bh*TT + t*128 + row)*HD + (u ^ (row & 7))*8,
            smem + (i*256 + w*64)*16);
    }
  };
  auto stageV = [&](int t) {
#pragma unroll
    for (int i = 0; i < 4; ++i) {
      int c = i*256 + tid; int row = c >> 4, u = c & 15;
      g2l16(vt + (size_t)(bh*HD + row)*TT + t*128 + (u ^ (row & 15))*8,
            smem + 16384 + (i*256 + w*64)*16);
    }
  };

  for (int ps = 0; ps < 2; ++ps) {
    int q0 = (ps ? (31 - ip) : ip) * 64;
    int qw = q0 + w * 16;
    const u16* qbase = q + (size_t)(bh*TT + qw + (l & 15))*HD + (l >> 4)*8;
    bf8 qf0 = *(const bf8*)(qbase);
    bf8 qf1 = *(const bf8*)(qbase + 32);
    float mreg[4] = {NEG_INF, NEG_INF, NEG_INF, NEG_INF};
    float lreg[4] = {0.f, 0.f, 0.f, 0.f};
    f4 z = {0.f, 0.f, 0.f, 0.f};
    f4 acc[4]; acc[0] = z; acc[1] = z; acc[2] = z; acc[3] = z;
    int nt = (q0 >> 7) + 1;                                // causal tile count
    stageK(0); stageV(0);                                  // outstanding: 8
    for (int t = 0; t < nt; ++t) {
      bool last = (t == nt - 1);
      VMCNT4();                                            // K(t) landed (V(t) may fly)
      SBAR();
      f4 sv[8];
#pragma unroll
      for (int jf = 0; jf < 8; ++jf) {                     // S = Q K^T
        f4 s = z;
        int row = jf*16 + (l & 15);
        int s0 = (l >> 4) ^ (row & 7);
        int s1 = ((l >> 4) + 4) ^ (row & 7);
        bf8 b0 = *(const bf8*)(smem + row*128 + s0*16);
        bf8 b1 = *(const bf8*)(smem + row*128 + s1*16);
        s = __builtin_amdgcn_mfma_f32_16x16x32_bf16(qf0, b0, s, 0, 0, 0);
        s = __builtin_amdgcn_mfma_f32_16x16x32_bf16(qf1, b1, s, 0, 0, 0);
        sv[jf] = s;
      }
      LGKMCNT0();                                          // K-buf reads drained
      SBAR();                                              // K-buf free for overwrite
      if (!last) stageK(t + 1);                            // overlap w/ softmax+PV
      bool need_mask = (t*128 + 127) > qw;                 // per-wave (R1 fix)
#pragma unroll
      for (int jf = 0; jf < 8; ++jf) {                     // scale + causal mask
        int key = t*128 + jf*16 + (l & 15);
#pragma unroll
        for (int r = 0; r < 4; ++r) {
          float val = sv[jf][r] * 0.125f;
          if (need_mask) {
            int qrow = qw + (l >> 4)*4 + r;
            if (key > qrow) val = NEG_INF;
          }
          sv[jf][r] = val;
        }
      }
      float alpha[4];
#pragma unroll
      for (int r = 0; r < 4; ++r) {                        // row max
        float mx = sv[0][r];
#pragma unroll
        for (int jf = 1; jf < 8; ++jf) mx = fmaxf(mx, sv[jf][r]);
#pragma unroll
        for (int d = 1; d < 16; d <<= 1) mx = fmaxf(mx, __shfl_xor(mx, d, 64));
        float mnew = fmaxf(mreg[r], mx);
        alpha[r] = __expf(mreg[r] - mnew);
        mreg[r] = mnew;
      }
      float rs[4] = {0.f, 0.f, 0.f, 0.f};
#pragma unroll
      for (int jf = 0; jf < 8; ++jf) {                     // P = exp(S-m) -> LDS bf16
        int col = jf*16 + (l & 15);
#pragma unroll
        for (int r = 0; r < 4; ++r) {
          float p = __expf(sv[jf][r] - mreg[r]);
          rs[r] += p;
          *(u16*)(Pb + ((l >> 4)*4 + r)*272 + col*2) = f2bf(p);
        }
      }
#pragma unroll
      for (int r = 0; r < 4; ++r) {
        float t_ = rs[r];
#pragma unroll
        for (int d = 1; d < 16; d <<= 1) t_ += __shfl_xor(t_, d, 64);
        lreg[r] = lreg[r]*alpha[r] + t_;
      }
#pragma unroll
      for (int df = 0; df < 4; ++df) {                     // rescale O
        f4 a = acc[df];
        a[0] *= alpha[0]; a[1] *= alpha[1]; a[2] *= alpha[2]; a[3] *= alpha[3];
        acc[df] = a;
      }
      if (!last) { VMCNT4(); } else { VMCNT0(); }          // V(t) landed
      SBAR();
#pragma unroll
      for (int ks = 0; ks < 4; ++ks) {                     // O += P V
        bf8 pf = *(const bf8*)(Pb + (l & 15)*272 + ks*64 + (l >> 4)*16);
#pragma unroll
        for (int df = 0; df < 4; ++df) {
          int row = df*16 + (l & 15);
          int sl = (ks*4 + (l >> 4)) ^ (row & 15);
          bf8 vf = *(const bf8*)(smem + 16384 + row*256 + sl*16);
          acc[df] = __builtin_amdgcn_mfma_f32_16x16x32_bf16(pf, vf, acc[df], 0, 0, 0);
        }
      }
      LGKMCNT0();                                          // V/P-buf reads drained
      SBAR();                                              // V-buf free for overwrite
      if (!last) stageV(t + 1);                            // overlap w/ next QK^T
    }
#pragma unroll
    for (int r = 0; r < 4; ++r) {                          // epilogue
      float inv = 1.0f / lreg[r];
      int t = q0 + w*16 + (l >> 4)*4 + r;
      u16* dst = ctx + (size_t)(b*TT + t)*DD + h*HD;
#pragma unroll
      for (int df = 0; df < 4; ++df)
        dst[df*16 + (l & 15)] = f2bf(acc[df][r] * inv);
    }
  }
}

// ---------------- output GEMM: ctx[4096,1024]bf16 @ WoT + bo -> fp32 ----------------
__global__ __launch_bounds__(256, 2) void k_out(const u16* __restrict__ ctx,
    const u16* __restrict__ wot, const float* __restrict__ bo, float* __restrict__ out) {
  __shared__ uint4 smem4[1024];
  char* smem = (char*)smem4;
  int tid = threadIdx.x, w = tid >> 6, l = tid & 63;
  int bid = blockIdx.y * 8 + blockIdx.x;                   // nwg=256
  int wg = (bid & 7) * 32 + (bid >> 3);
  int nb = wg % 8, mb = wg / 8;
  int wm = w >> 1, wn = w & 1;
  f4 z = {0.f, 0.f, 0.f, 0.f};
  f4 acc[4][4];
#pragma unroll
  for (int i = 0; i < 4; ++i)
#pragma unroll
    for (int j = 0; j < 4; ++j) acc[i][j] = z;

  for (int kt = 0; kt < 32; ++kt) {
    int kkk = kt * 32;
    __syncthreads();
#pragma unroll
    for (int i = 0; i < 2; ++i) {
      int c = i*256 + tid; int row = c >> 2, u = c & 3, s = u ^ ((row >> 1) & 3);
      g2l16(ctx + (size_t)(mb*128 + row)*DD + kkk + s*8, smem + (i*256 + w*64)*16);
    }
#pragma unroll
    for (int i = 0; i < 2; ++i) {
      int c = i*256 + tid; int row = c >> 2, u = c & 3, s = u ^ ((row >> 1) & 3);
      g2l16(wot + (size_t)(nb*128 + row)*DD + kkk + s*8, smem + 8192 + (i*256 + w*64)*16);
    }
    __syncthreads();
    bf8 af[4], bfr[4];
#pragma unroll
    for (int mf = 0; mf < 4; ++mf) {
      int row = wm*64 + mf*16 + (l & 15);
      int s = (l >> 4) ^ ((row >> 1) & 3);
      af[mf] = *(const bf8*)(smem + row*64 + s*16);
    }
#pragma unroll
    for (int nf = 0; nf < 4; ++nf) {
      int row = wn*64 + nf*16 + (l & 15);
      int s = (l >> 4) ^ ((row >> 1) & 3);
      bfr[nf] = *(const bf8*)(smem + 8192 + row*64 + s*16);
    }
#pragma unroll
    for (int mf = 0; mf < 4; ++mf)
#pragma unroll
      for (int nf = 0; nf < 4; ++nf)
        acc[mf][nf] = __builtin_amdgcn_mfma_f32_16x16x32_bf16(af[mf], bfr[nf], acc[mf][nf], 0, 0, 0);
  }
#pragma unroll
  for (int nf = 0; nf < 4; ++nf) {
    int n = nb*128 + wn*64 + nf*16 + (l & 15);
    float bias = bo[n];
#pragma unroll
    for (int mf = 0; mf < 4; ++mf) {
      int m0 = mb*128 + wm*64 + mf*16 + (l >> 4)*4;
#pragma unroll
      for (int r = 0; r < 4; ++r)
        out[(size_t)(m0 + r)*DD + n] = acc[mf][nf][r] + bias;
    }
  }
}

extern "C" void kernel_launch(void* const* d_in, const int* in_sizes, int n_in,
                              void* d_out, int out_size, void* d_ws, size_t ws_size,
                              hipStream_t stream) {
  const float* x  = (const float*)d_in[0];
  const float* Wq = (const float*)d_in[1];
  const float* Wk = (const float*)d_in[2];
  const float* Wv = (const float*)d_in[3];
  const float* Wo = (const float*)d_in[4];
  const float* bo = (const float*)d_in[5];
  float* out = (float*)d_out;
  char* ws = (char*)d_ws;

  u16* xb  = (u16*)(ws);                                   // 8 MB bf16 x
  u16* wqt = (u16*)(ws + 8388608);                         // 2 MB each, transposed bf16
  u16* wkt = (u16*)(ws + 10485760);
  u16* wvt = (u16*)(ws + 12582912);
  u16* wot = (u16*)(ws + 14680064);
  u16* qb_ = (u16*)(ws + 16777216);                        // 8 MB [bh][t][64]
  u16* kb_ = (u16*)(ws + 25165824);
  u16* vb_ = (u16*)(ws + 33554432);
  u16* vtb = (u16*)(ws + 41943040);                        // 8 MB [bh][64][t]
  u16* cxb = (u16*)(ws + 50331648);                        // 8 MB [b*t][1024]

  k_cast_x<<<dim3(2048), dim3(256), 0, stream>>>(x, (uint4*)xb);
  k_twcast<<<dim3(16, 16, 4), dim3(256), 0, stream>>>(Wq, Wk, Wv, Wo, wqt, wkt, wvt, wot);
  k_qkv<<<dim3(24, 32), dim3(256), 0, stream>>>(xb, wqt, wkt, wvt, qb_, kb_, vb_);
  k_vt<<<dim3(32, 32), dim3(256), 0, stream>>>(vb_, vtb);
  k_attn<<<dim3(512), dim3(256), 0, stream>>>(qb_, kb_, vtb, cxb);
  k_out<<<dim3(8, 32), dim3(256), 0, stream>>>(cxb, wot, bo, out);
}

// Round 6
// 184.811 us; speedup vs baseline: 1.2857x; 1.0820x over previous
//
#include <hip/hip_runtime.h>
#include <stdint.h>

typedef unsigned short u16;
typedef unsigned int   u32;
typedef __attribute__((ext_vector_type(8))) __bf16 bf8;   // 8 bf16 = 4 VGPR (MFMA A/B frag)
typedef __attribute__((ext_vector_type(4))) float  f4;    // MFMA C/D frag

#define NEG_INF (-__builtin_inff())

// sizes
#define BB 2
#define TT 2048
#define DD 1024
#define HH 16
#define HD 64
#define BT (BB*TT)   // 4096

#define SBAR() __builtin_amdgcn_s_barrier()
#define VMCNT4() asm volatile("s_waitcnt vmcnt(4)" ::: "memory")
#define VMCNT0() asm volatile("s_waitcnt vmcnt(0)" ::: "memory")
#define LGKMCNT0() asm volatile("s_waitcnt lgkmcnt(0)" ::: "memory")

__device__ __forceinline__ u16 f2bf(float f) {            // RNE fp32->bf16 (inputs finite)
  u32 u = __builtin_bit_cast(u32, f);
  u += 0x7FFFu + ((u >> 16) & 1u);
  return (u16)(u >> 16);
}

__device__ __forceinline__ float exp2fast(float x) {      // native v_exp_f32 (= 2^x)
  float r; asm("v_exp_f32 %0, %1" : "=v"(r) : "v"(x)); return r;
}

__device__ __forceinline__ void g2l16(const void* g, void* l) {
  // async global->LDS, 16B per lane; LDS dest = wave-uniform base + lane*16
  __builtin_amdgcn_global_load_lds((const __attribute__((address_space(1))) u32*)g,
                                   (__attribute__((address_space(3))) u32*)l, 16, 0, 0);
}

// ---------------- cast x: fp32 -> bf16, 8 elems/thread ----------------
__global__ void k_cast_x(const float* __restrict__ x, uint4* __restrict__ xb) {
  int i = blockIdx.x * 256 + threadIdx.x;                  // 524288 threads exactly
  const float4* xf = (const float4*)x;
  float4 a = xf[2*i], b = xf[2*i+1];
  uint4 o;
  o.x = (u32)f2bf(a.x) | ((u32)f2bf(a.y) << 16);
  o.y = (u32)f2bf(a.z) | ((u32)f2bf(a.w) << 16);
  o.z = (u32)f2bf(b.x) | ((u32)f2bf(b.y) << 16);
  o.w = (u32)f2bf(b.z) | ((u32)f2bf(b.w) << 16);
  xb[i] = o;
}

// ------------- transpose+cast weights: W[k][n] f32 -> WT[n][k] bf16 -------------
__global__ void k_twcast(const float* __restrict__ w0, const float* __restrict__ w1,
                         const float* __restrict__ w2, const float* __restrict__ w3,
                         u16* __restrict__ o0, u16* __restrict__ o1,
                         u16* __restrict__ o2, u16* __restrict__ o3) {
  const float* W; u16* O;
  switch (blockIdx.z) {
    case 0: W = w0; O = o0; break;
    case 1: W = w1; O = o1; break;
    case 2: W = w2; O = o2; break;
    default: W = w3; O = o3; break;
  }
  __shared__ __align__(16) u16 tile[64][80];
  int tid = threadIdx.x;
  int k0 = blockIdx.y * 64, n0 = blockIdx.x * 64;
#pragma unroll
  for (int it = 0; it < 4; ++it) {                         // load 64x64 f32, cast
    int c = it*256 + tid; int kr = c >> 4, ns = c & 15;
    float4 v = *(const float4*)(W + (size_t)(k0+kr)*DD + n0 + ns*4);
    u16* p = &tile[kr][ns*4];
    p[0] = f2bf(v.x); p[1] = f2bf(v.y); p[2] = f2bf(v.z); p[3] = f2bf(v.w);
  }
  __syncthreads();
#pragma unroll
  for (int it = 0; it < 2; ++it) {                         // store transposed bf16
    int c = it*256 + tid; int nr = c >> 3, ks = c & 7;
    u32 ww[4];
#pragma unroll
    for (int e = 0; e < 4; ++e) {
      u16 lo = tile[ks*8 + 2*e][nr], hi = tile[ks*8 + 2*e + 1][nr];
      ww[e] = (u32)lo | ((u32)hi << 16);
    }
    uint4 o; o.x = ww[0]; o.y = ww[1]; o.z = ww[2]; o.w = ww[3];
    *(uint4*)(O + (size_t)(n0+nr)*DD + k0 + ks*8) = o;
  }
}

// ---------------- fused QKV GEMM: X[4096,1024]bf16 @ {WqT,WkT,WvT} ----------------
// Q written pre-scaled by 0.125*log2e (attn runs softmax in log2 domain).
// V written directly transposed [bh][d][t] (k_vt eliminated).
__global__ __launch_bounds__(256, 2) void k_qkv(const u16* __restrict__ xb,
    const u16* __restrict__ wqt, const u16* __restrict__ wkt, const u16* __restrict__ wvt,
    u16* __restrict__ qo, u16* __restrict__ ko, u16* __restrict__ vo) {
  __shared__ uint4 smem4[1024];                            // A 8KB | B 8KB
  char* smem = (char*)smem4;
  int tid = threadIdx.x, w = tid >> 6, l = tid & 63;
  int bid = blockIdx.y * 24 + blockIdx.x;                  // nwg=768, XCD swizzle (768%8==0)
  int wg = (bid & 7) * 96 + (bid >> 3);
  int nb = wg % 24, mb = wg / 24;
  const u16* Bt = (nb < 8) ? wqt : (nb < 16 ? wkt : wvt);
  int nbl = nb & 7;
  int wm = w >> 1, wn = w & 1;
  f4 z = {0.f, 0.f, 0.f, 0.f};
  f4 acc[4][4];
#pragma unroll
  for (int i = 0; i < 4; ++i)
#pragma unroll
    for (int j = 0; j < 4; ++j) acc[i][j] = z;

  for (int kt = 0; kt < 32; ++kt) {
    int kk = kt * 32;
    __syncthreads();
#pragma unroll
    for (int i = 0; i < 2; ++i) {                          // stage A (swizzled source)
      int c = i*256 + tid; int row = c >> 2, u = c & 3, s = u ^ ((row >> 1) & 3);
      g2l16(xb + (size_t)(mb*128 + row)*DD + kk + s*8, smem + (i*256 + w*64)*16);
    }
#pragma unroll
    for (int i = 0; i < 2; ++i) {                          // stage B
      int c = i*256 + tid; int row = c >> 2, u = c & 3, s = u ^ ((row >> 1) & 3);
      g2l16(Bt + (size_t)(nbl*128 + row)*DD + kk + s*8, smem + 8192 + (i*256 + w*64)*16);
    }
    __syncthreads();
    bf8 af[4], bfr[4];
#pragma unroll
    for (int mf = 0; mf < 4; ++mf) {
      int row = wm*64 + mf*16 + (l & 15);
      int s = (l >> 4) ^ ((row >> 1) & 3);
      af[mf] = *(const bf8*)(smem + row*64 + s*16);
    }
#pragma unroll
    for (int nf = 0; nf < 4; ++nf) {
      int row = wn*64 + nf*16 + (l & 15);
      int s = (l >> 4) ^ ((row >> 1) & 3);
      bfr[nf] = *(const bf8*)(smem + 8192 + row*64 + s*16);
    }
#pragma unroll
    for (int mf = 0; mf < 4; ++mf)
#pragma unroll
      for (int nf = 0; nf < 4; ++nf)
        acc[mf][nf] = __builtin_amdgcn_mfma_f32_16x16x32_bf16(af[mf], bfr[nf], acc[mf][nf], 0, 0, 0);
  }
  if (nb < 16) {                                           // Q (pre-scaled) or K
    u16* Out = (nb < 8) ? qo : ko;
    float qs = (nb < 8) ? 0.18033688011112042f : 1.0f;     // 0.125*log2(e) for Q
#pragma unroll
    for (int mf = 0; mf < 4; ++mf) {
      int m0 = mb*128 + wm*64 + mf*16 + (l >> 4)*4;
      int b = m0 >> 11;
#pragma unroll
      for (int nf = 0; nf < 4; ++nf) {
        int nn = nbl*128 + wn*64 + nf*16 + (l & 15);
        int h = nn >> 6, d = nn & 63;
#pragma unroll
        for (int r = 0; r < 4; ++r) {
          int t = (m0 + r) & 2047;
          Out[(size_t)((b*HH + h)*TT + t)*HD + d] = f2bf(acc[mf][nf][r] * qs);
        }
      }
    }
  } else {                                                 // V: write transposed [bh][d][t]
#pragma unroll
    for (int mf = 0; mf < 4; ++mf) {
      int m0 = mb*128 + wm*64 + mf*16 + (l >> 4)*4;
      int b = m0 >> 11, t0 = m0 & 2047;
#pragma unroll
      for (int nf = 0; nf < 4; ++nf) {
        int nn = nbl*128 + wn*64 + nf*16 + (l & 15);
        int h = nn >> 6, d = nn & 63;
        uint2 o;
        o.x = (u32)f2bf(acc[mf][nf][0]) | ((u32)f2bf(acc[mf][nf][1]) << 16);
        o.y = (u32)f2bf(acc[mf][nf][2]) | ((u32)f2bf(acc[mf][nf][3]) << 16);
        *(uint2*)(vo + (size_t)((b*HH + h)*HD + d)*TT + t0) = o;
      }
    }
  }
}

// ---------------- flash attention, causal; swapped-QK^T in-register softmax ----------------
// Per iter: Ssw = mfma(K,Q) -> lane owns q=l&15, keys {jf*16+4g+r}. Row-reduce:
// in-lane chain + 2 shuffles. P packed u32 -> LDS [16 q][68 u32] XOR-col, read
// back as b128 B-frags for O^T = mfma(V^T, P^T). Q pre-scaled; exp = v_exp_f32.
__global__ __launch_bounds__(256, 2) void k_attn(const u16* __restrict__ q,
    const u16* __restrict__ kk, const u16* __restrict__ vt, u16* __restrict__ ctx) {
  __shared__ __align__(16) char smem[50176];               // K 16K | V 16K | P 4x4352
  int tid = threadIdx.x, w = tid >> 6, l = tid & 63;
  int qi = l & 15, g = l >> 4;
  int fid = blockIdx.x;
  int xcd = fid & 7, j = fid >> 3;
  int bh  = xcd * 4 + (j & 3);                             // 4 bh per XCD
  int ip  = j >> 2;                                        // 0..15 pair index
  u32* Pw = (u32*)(smem + 32768) + w * 1088;               // per-wave [16 q][68 u32]
  int b = bh >> 4, h = bh & 15;
  u32 colx = ((u32)(qi & 3)) << 2;                         // bank-spread XOR (bits 2-3)

  auto stageK = [&](int t) {
#pragma unroll
    for (int i = 0; i < 4; ++i) {
      int c = i*256 + tid; int row = c >> 3, u = c & 7;
      g2l16(kk + (size_t)(bh*TT + t*128 + row)*HD + (u ^ (row & 7))*8,
            smem + (i*256 + w*64)*16);
    }
  };
  auto stageV = [&](int t) {
#pragma unroll
    for (int i = 0; i < 4; ++i) {
      int c = i*256 + tid; int row = c >> 4, u = c & 15;
      g2l16(vt + (size_t)(bh*HD + row)*TT + t*128 + (u ^ (row & 15))*8,
            smem + 16384 + (i*256 + w*64)*16);
    }
  };

  for (int ps = 0; ps < 2; ++ps) {
    int q0 = (ps ? (31 - ip) : ip) * 64;
    int qw = q0 + w * 16;
    int qrow = qw + qi;
    const u16* qbase = q + (size_t)(bh*TT + qrow)*HD + g*8;
    bf8 qf0 = *(const bf8*)(qbase);                        // d 0..31 (8g..8g+7)
    bf8 qf1 = *(const bf8*)(qbase + 32);                   // d 32..63
    float mreg = NEG_INF, lreg = 0.f;
    f4 z = {0.f, 0.f, 0.f, 0.f};
    f4 acc[4]; acc[0] = z; acc[1] = z; acc[2] = z; acc[3] = z;
    int nt = (q0 >> 7) + 1;                                // causal tile count
    stageK(0); stageV(0);                                  // outstanding: 8 instrs
    for (int t = 0; t < nt; ++t) {
      bool last = (t == nt - 1);
      VMCNT4();                                            // K(t) landed (V(t) may fly)
      SBAR();
      __builtin_amdgcn_s_setprio(1);
      f4 sv[8];
#pragma unroll
      for (int jf = 0; jf < 8; ++jf) {                     // Ssw = K Q^T (swapped operands)
        f4 s = z;
        int row = jf*16 + qi;
        int s0 = g ^ (row & 7);
        int s1 = (g + 4) ^ (row & 7);
        bf8 b0 = *(const bf8*)(smem + row*128 + s0*16);
        bf8 b1 = *(const bf8*)(smem + row*128 + s1*16);
        s = __builtin_amdgcn_mfma_f32_16x16x32_bf16(b0, qf0, s, 0, 0, 0);
        s = __builtin_amdgcn_mfma_f32_16x16x32_bf16(b1, qf1, s, 0, 0, 0);
        sv[jf] = s;                                        // key = jf*16+4g+r, q = qi
      }
      __builtin_amdgcn_s_setprio(0);
      LGKMCNT0();                                          // K-buf reads drained
      SBAR();                                              // K-buf free for overwrite
      if (!last) stageK(t + 1);                            // overlap w/ softmax+PV
      if (t*128 + 127 > qw) {                              // diagonal tile: causal mask
        int cbase = qrow - t*128 - 4*g;                    // mask where jf*16+r > cbase
#pragma unroll
        for (int jf = 0; jf < 8; ++jf)
#pragma unroll
          for (int r = 0; r < 4; ++r)
            if (jf*16 + r > cbase) sv[jf][r] = NEG_INF;
      }
      float mx = NEG_INF;                                  // row max: in-lane + cross-g
#pragma unroll
      for (int jf = 0; jf < 8; ++jf)
        mx = fmaxf(mx, fmaxf(fmaxf(sv[jf][0], sv[jf][1]), fmaxf(sv[jf][2], sv[jf][3])));
      mx = fmaxf(mx, __shfl_xor(mx, 16, 64));
      mx = fmaxf(mx, __shfl_xor(mx, 32, 64));
      float mnew = fmaxf(mreg, mx);
      float alpha = exp2fast(mreg - mnew);
      mreg = mnew;
      float rs = 0.f;
#pragma unroll
      for (int jf = 0; jf < 8; ++jf) {                     // P = 2^(S-m), pack -> LDS
        float p0 = exp2fast(sv[jf][0] - mreg);
        float p1 = exp2fast(sv[jf][1] - mreg);
        float p2 = exp2fast(sv[jf][2] - mreg);
        float p3 = exp2fast(sv[jf][3] - mreg);
        rs += (p0 + p1) + (p2 + p3);
        u32 pk0 = (u32)f2bf(p0) | ((u32)f2bf(p1) << 16);   // keys jf*16+4g+{0,1}
        u32 pk1 = (u32)f2bf(p2) | ((u32)f2bf(p3) << 16);   // keys jf*16+4g+{2,3}
        Pw[qi*68 + ((u32)(jf*8 + 2*g + 0) ^ colx)] = pk0;
        Pw[qi*68 + ((u32)(jf*8 + 2*g + 1) ^ colx)] = pk1;
      }
      rs += __shfl_xor(rs, 16, 64);
      rs += __shfl_xor(rs, 32, 64);
      lreg = lreg * alpha + rs;
#pragma unroll
      for (int df = 0; df < 4; ++df) {                     // rescale O^T accumulator
        f4 a = acc[df];
        a[0] *= alpha; a[1] *= alpha; a[2] *= alpha; a[3] *= alpha;
        acc[df] = a;
      }
      if (!last) { VMCNT4(); } else { VMCNT0(); }          // V(t) landed
      SBAR();
      __builtin_amdgcn_s_setprio(1);
#pragma unroll
      for (int ks = 0; ks < 4; ++ks) {                     // O^T += V^T P^T
        bf8 pf = *(const bf8*)(Pw + qi*68 + ((u32)(ks*16 + 4*g) ^ colx));
#pragma unroll
        for (int df = 0; df < 4; ++df) {
          int row = df*16 + qi;
          int sl = (ks*4 + g) ^ (row & 15);
          bf8 vf = *(const bf8*)(smem + 16384 + row*256 + sl*16);
          acc[df] = __builtin_amdgcn_mfma_f32_16x16x32_bf16(vf, pf, acc[df], 0, 0, 0);
        }
      }
      __builtin_amdgcn_s_setprio(0);
      LGKMCNT0();                                          // V/P reads drained
      SBAR();                                              // V-buf free for overwrite
      if (!last) stageV(t + 1);                            // overlap w/ next QK^T
    }
    float inv = 1.0f / lreg;                               // epilogue: d = df*16+4g+r
    u16* dst = ctx + (size_t)(b*TT + qrow)*DD + h*HD;
#pragma unroll
    for (int df = 0; df < 4; ++df) {
      uint2 o;
      o.x = (u32)f2bf(acc[df][0] * inv) | ((u32)f2bf(acc[df][1] * inv) << 16);
      o.y = (u32)f2bf(acc[df][2] * inv) | ((u32)f2bf(acc[df][3] * inv) << 16);
      *(uint2*)(dst + df*16 + 4*g) = o;
    }
  }
}

// ---------------- output GEMM: ctx[4096,1024]bf16 @ WoT + bo -> fp32 ----------------
__global__ __launch_bounds__(256, 2) void k_out(const u16* __restrict__ ctx,
    const u16* __restrict__ wot, const float* __restrict__ bo, float* __restrict__ out) {
  __shared__ uint4 smem4[1024];
  char* smem = (char*)smem4;
  int tid = threadIdx.x, w = tid >> 6, l = tid & 63;
  int bid = blockIdx.y * 8 + blockIdx.x;                   // nwg=256
  int wg = (bid & 7) * 32 + (bid >> 3);
  int nb = wg % 8, mb = wg / 8;
  int wm = w >> 1, wn = w & 1;
  f4 z = {0.f, 0.f, 0.f, 0.f};
  f4 acc[4][4];
#pragma unroll
  for (int i = 0; i < 4; ++i)
#pragma unroll
    for (int j = 0; j < 4; ++j) acc[i][j] = z;

  for (int kt = 0; kt < 32; ++kt) {
    int kkk = kt * 32;
    __syncthreads();
#pragma unroll
    for (int i = 0; i < 2; ++i) {
      int c = i*256 + tid; int row = c >> 2, u = c & 3, s = u ^ ((row >> 1) & 3);
      g2l16(ctx + (size_t)(mb*128 + row)*DD + kkk + s*8, smem + (i*256 + w*64)*16);
    }
#pragma unroll
    for (int i = 0; i < 2; ++i) {
      int c = i*256 + tid; int row = c >> 2, u = c & 3, s = u ^ ((row >> 1) & 3);
      g2l16(wot + (size_t)(nb*128 + row)*DD + kkk + s*8, smem + 8192 + (i*256 + w*64)*16);
    }
    __syncthreads();
    bf8 af[4], bfr[4];
#pragma unroll
    for (int mf = 0; mf < 4; ++mf) {
      int row = wm*64 + mf*16 + (l & 15);
      int s = (l >> 4) ^ ((row >> 1) & 3);
      af[mf] = *(const bf8*)(smem + row*64 + s*16);
    }
#pragma unroll
    for (int nf = 0; nf < 4; ++nf) {
      int row = wn*64 + nf*16 + (l & 15);
      int s = (l >> 4) ^ ((row >> 1) & 3);
      bfr[nf] = *(const bf8*)(smem + 8192 + row*64 + s*16);
    }
#pragma unroll
    for (int mf = 0; mf < 4; ++mf)
#pragma unroll
      for (int nf = 0; nf < 4; ++nf)
        acc[mf][nf] = __builtin_amdgcn_mfma_f32_16x16x32_bf16(af[mf], bfr[nf], acc[mf][nf], 0, 0, 0);
  }
#pragma unroll
  for (int nf = 0; nf < 4; ++nf) {
    int n = nb*128 + wn*64 + nf*16 + (l & 15);
    float bias = bo[n];
#pragma unroll
    for (int mf = 0; mf < 4; ++mf) {
      int m0 = mb*128 + wm*64 + mf*16 + (l >> 4)*4;
#pragma unroll
      for (int r = 0; r < 4; ++r)
        out[(size_t)(m0 + r)*DD + n] = acc[mf][nf][r] + bias;
    }
  }
}

extern "C" void kernel_launch(void* const* d_in, const int* in_sizes, int n_in,
                              void* d_out, int out_size, void* d_ws, size_t ws_size,
                              hipStream_t stream) {
  const float* x  = (const float*)d_in[0];
  const float* Wq = (const float*)d_in[1];
  const float* Wk = (const float*)d_in[2];
  const float* Wv = (const float*)d_in[3];
  const float* Wo = (const float*)d_in[4];
  const float* bo = (const float*)d_in[5];
  float* out = (float*)d_out;
  char* ws = (char*)d_ws;

  u16* xb  = (u16*)(ws);                                   // 8 MB bf16 x
  u16* wqt = (u16*)(ws + 8388608);                         // 2 MB each, transposed bf16
  u16* wkt = (u16*)(ws + 10485760);
  u16* wvt = (u16*)(ws + 12582912);
  u16* wot = (u16*)(ws + 14680064);
  u16* qb_ = (u16*)(ws + 16777216);                        // 8 MB [bh][t][64], pre-scaled
  u16* kb_ = (u16*)(ws + 25165824);                        // 8 MB [bh][t][64]
  u16* vtb = (u16*)(ws + 41943040);                        // 8 MB [bh][64][t] (from k_qkv)
  u16* cxb = (u16*)(ws + 50331648);                        // 8 MB [b*t][1024]

  k_cast_x<<<dim3(2048), dim3(256), 0, stream>>>(x, (uint4*)xb);
  k_twcast<<<dim3(16, 16, 4), dim3(256), 0, stream>>>(Wq, Wk, Wv, Wo, wqt, wkt, wvt, wot);
  k_qkv<<<dim3(24, 32), dim3(256), 0, stream>>>(xb, wqt, wkt, wvt, qb_, kb_, vtb);
  k_attn<<<dim3(512), dim3(256), 0, stream>>>(qb_, kb_, vtb, cxb);
  k_out<<<dim3(8, 32), dim3(256), 0, stream>>>(cxb, wot, bo, out);
}

// Round 7
// 182.544 us; speedup vs baseline: 1.3017x; 1.0124x over previous
//
#include <hip/hip_runtime.h>
#include <stdint.h>

typedef unsigned short u16;
typedef unsigned int   u32;
typedef __attribute__((ext_vector_type(8))) __bf16 bf8;   // 8 bf16 = 4 VGPR (MFMA A/B frag)
typedef __attribute__((ext_vector_type(4))) float  f4;    // MFMA C/D frag

#define NEG_INF (-__builtin_inff())

// sizes
#define BB 2
#define TT 2048
#define DD 1024
#define HH 16
#define HD 64
#define BT (BB*TT)   // 4096

#define SBAR() __builtin_amdgcn_s_barrier()
#define VMCNT4() asm volatile("s_waitcnt vmcnt(4)" ::: "memory")
#define VMCNT0() asm volatile("s_waitcnt vmcnt(0)" ::: "memory")
#define LGKMCNT0() asm volatile("s_waitcnt lgkmcnt(0)" ::: "memory")

__device__ __forceinline__ u16 f2bf(float f) {            // RNE fp32->bf16 (inputs finite)
  u32 u = __builtin_bit_cast(u32, f);
  u += 0x7FFFu + ((u >> 16) & 1u);
  return (u16)(u >> 16);
}

__device__ __forceinline__ float exp2fast(float x) {      // native v_exp_f32 (= 2^x)
  float r; asm("v_exp_f32 %0, %1" : "=v"(r) : "v"(x)); return r;
}

__device__ __forceinline__ void g2l16(const void* g, void* l) {
  // async global->LDS, 16B per lane; LDS dest = wave-uniform base + lane*16
  __builtin_amdgcn_global_load_lds((const __attribute__((address_space(1))) u32*)g,
                                   (__attribute__((address_space(3))) u32*)l, 16, 0, 0);
}

// ---------------- cast x: fp32 -> bf16, 8 elems/thread ----------------
__global__ void k_cast_x(const float* __restrict__ x, uint4* __restrict__ xb) {
  int i = blockIdx.x * 256 + threadIdx.x;                  // 524288 threads exactly
  const float4* xf = (const float4*)x;
  float4 a = xf[2*i], b = xf[2*i+1];
  uint4 o;
  o.x = (u32)f2bf(a.x) | ((u32)f2bf(a.y) << 16);
  o.y = (u32)f2bf(a.z) | ((u32)f2bf(a.w) << 16);
  o.z = (u32)f2bf(b.x) | ((u32)f2bf(b.y) << 16);
  o.w = (u32)f2bf(b.z) | ((u32)f2bf(b.w) << 16);
  xb[i] = o;
}

// ------------- transpose+cast weights: W[k][n] f32 -> WT[n][k] bf16 -------------
__global__ void k_twcast(const float* __restrict__ w0, const float* __restrict__ w1,
                         const float* __restrict__ w2, const float* __restrict__ w3,
                         u16* __restrict__ o0, u16* __restrict__ o1,
                         u16* __restrict__ o2, u16* __restrict__ o3) {
  const float* W; u16* O;
  switch (blockIdx.z) {
    case 0: W = w0; O = o0; break;
    case 1: W = w1; O = o1; break;
    case 2: W = w2; O = o2; break;
    default: W = w3; O = o3; break;
  }
  __shared__ __align__(16) u16 tile[64][80];
  int tid = threadIdx.x;
  int k0 = blockIdx.y * 64, n0 = blockIdx.x * 64;
#pragma unroll
  for (int it = 0; it < 4; ++it) {                         // load 64x64 f32, cast
    int c = it*256 + tid; int kr = c >> 4, ns = c & 15;
    float4 v = *(const float4*)(W + (size_t)(k0+kr)*DD + n0 + ns*4);
    u16* p = &tile[kr][ns*4];
    p[0] = f2bf(v.x); p[1] = f2bf(v.y); p[2] = f2bf(v.z); p[3] = f2bf(v.w);
  }
  __syncthreads();
#pragma unroll
  for (int it = 0; it < 2; ++it) {                         // store transposed bf16
    int c = it*256 + tid; int nr = c >> 3, ks = c & 7;
    u32 ww[4];
#pragma unroll
    for (int e = 0; e < 4; ++e) {
      u16 lo = tile[ks*8 + 2*e][nr], hi = tile[ks*8 + 2*e + 1][nr];
      ww[e] = (u32)lo | ((u32)hi << 16);
    }
    uint4 o; o.x = ww[0]; o.y = ww[1]; o.z = ww[2]; o.w = ww[3];
    *(uint4*)(O + (size_t)(n0+nr)*DD + k0 + ks*8) = o;
  }
}

// ---------------- fused QKV GEMM: X[4096,1024]bf16 @ {WqT,WkT,WvT} ----------------
// Q written pre-scaled by 0.125*log2e (attn runs softmax in log2 domain).
// V written directly transposed [bh][d][t] (k_vt eliminated).
__global__ __launch_bounds__(256, 2) void k_qkv(const u16* __restrict__ xb,
    const u16* __restrict__ wqt, const u16* __restrict__ wkt, const u16* __restrict__ wvt,
    u16* __restrict__ qo, u16* __restrict__ ko, u16* __restrict__ vo) {
  __shared__ uint4 smem4[1024];                            // A 8KB | B 8KB
  char* smem = (char*)smem4;
  int tid = threadIdx.x, w = tid >> 6, l = tid & 63;
  int bid = blockIdx.y * 24 + blockIdx.x;                  // nwg=768, XCD swizzle (768%8==0)
  int wg = (bid & 7) * 96 + (bid >> 3);
  int nb = wg % 24, mb = wg / 24;
  const u16* Bt = (nb < 8) ? wqt : (nb < 16 ? wkt : wvt);
  int nbl = nb & 7;
  int wm = w >> 1, wn = w & 1;
  f4 z = {0.f, 0.f, 0.f, 0.f};
  f4 acc[4][4];
#pragma unroll
  for (int i = 0; i < 4; ++i)
#pragma unroll
    for (int j = 0; j < 4; ++j) acc[i][j] = z;

  for (int kt = 0; kt < 32; ++kt) {
    int kk = kt * 32;
    __syncthreads();
#pragma unroll
    for (int i = 0; i < 2; ++i) {                          // stage A (swizzled source)
      int c = i*256 + tid; int row = c >> 2, u = c & 3, s = u ^ ((row >> 1) & 3);
      g2l16(xb + (size_t)(mb*128 + row)*DD + kk + s*8, smem + (i*256 + w*64)*16);
    }
#pragma unroll
    for (int i = 0; i < 2; ++i) {                          // stage B
      int c = i*256 + tid; int row = c >> 2, u = c & 3, s = u ^ ((row >> 1) & 3);
      g2l16(Bt + (size_t)(nbl*128 + row)*DD + kk + s*8, smem + 8192 + (i*256 + w*64)*16);
    }
    __syncthreads();
    bf8 af[4], bfr[4];
#pragma unroll
    for (int mf = 0; mf < 4; ++mf) {
      int row = wm*64 + mf*16 + (l & 15);
      int s = (l >> 4) ^ ((row >> 1) & 3);
      af[mf] = *(const bf8*)(smem + row*64 + s*16);
    }
#pragma unroll
    for (int nf = 0; nf < 4; ++nf) {
      int row = wn*64 + nf*16 + (l & 15);
      int s = (l >> 4) ^ ((row >> 1) & 3);
      bfr[nf] = *(const bf8*)(smem + 8192 + row*64 + s*16);
    }
#pragma unroll
    for (int mf = 0; mf < 4; ++mf)
#pragma unroll
      for (int nf = 0; nf < 4; ++nf)
        acc[mf][nf] = __builtin_amdgcn_mfma_f32_16x16x32_bf16(af[mf], bfr[nf], acc[mf][nf], 0, 0, 0);
  }
  if (nb < 16) {                                           // Q (pre-scaled) or K
    u16* Out = (nb < 8) ? qo : ko;
    float qs = (nb < 8) ? 0.18033688011112042f : 1.0f;     // 0.125*log2(e) for Q
#pragma unroll
    for (int mf = 0; mf < 4; ++mf) {
      int m0 = mb*128 + wm*64 + mf*16 + (l >> 4)*4;
      int b = m0 >> 11;
#pragma unroll
      for (int nf = 0; nf < 4; ++nf) {
        int nn = nbl*128 + wn*64 + nf*16 + (l & 15);
        int h = nn >> 6, d = nn & 63;
#pragma unroll
        for (int r = 0; r < 4; ++r) {
          int t = (m0 + r) & 2047;
          Out[(size_t)((b*HH + h)*TT + t)*HD + d] = f2bf(acc[mf][nf][r] * qs);
        }
      }
    }
  } else {                                                 // V: write transposed [bh][d][t]
#pragma unroll
    for (int mf = 0; mf < 4; ++mf) {
      int m0 = mb*128 + wm*64 + mf*16 + (l >> 4)*4;
      int b = m0 >> 11, t0 = m0 & 2047;
#pragma unroll
      for (int nf = 0; nf < 4; ++nf) {
        int nn = nbl*128 + wn*64 + nf*16 + (l & 15);
        int h = nn >> 6, d = nn & 63;
        uint2 o;
        o.x = (u32)f2bf(acc[mf][nf][0]) | ((u32)f2bf(acc[mf][nf][1]) << 16);
        o.y = (u32)f2bf(acc[mf][nf][2]) | ((u32)f2bf(acc[mf][nf][3]) << 16);
        *(uint2*)(vo + (size_t)((b*HH + h)*HD + d)*TT + t0) = o;
      }
    }
  }
}

// ---------------- flash attention, causal; swapped-QK^T in-register softmax ----------------
// P LDS layout (R7 fix): per-wave [16 q][68 u32] with ADDITIVE 4-word-block
// rotation: physical blk = (logical blk + 2*(qi&7)) & 15. Write bank group
// (-a+2jf+u) mod 8 and read bank group (-a+g) mod 8 are bijections in a=qi&7
// -> b64 writes 4/bank uniform, b128 reads 8/bank uniform (both minimum).
// R6's colx XOR had 8-way write collisions (SQ_LDS_BANK_CONFLICT 7.24M).
__global__ __launch_bounds__(256, 2) void k_attn(const u16* __restrict__ q,
    const u16* __restrict__ kk, const u16* __restrict__ vt, u16* __restrict__ ctx) {
  __shared__ __align__(16) char smem[50176];               // K 16K | V 16K | P 4x4352
  int tid = threadIdx.x, w = tid >> 6, l = tid & 63;
  int qi = l & 15, g = l >> 4;
  int fid = blockIdx.x;
  int xcd = fid & 7, j = fid >> 3;
  int bh  = xcd * 4 + (j & 3);                             // 4 bh per XCD
  int ip  = j >> 2;                                        // 0..15 pair index
  u32* Pw = (u32*)(smem + 32768) + w * 1088;               // per-wave [16 q][68 u32]
  int b = bh >> 4, h = bh & 15;
  int rot2 = 2 * (qi & 7);                                 // additive block rotation

  auto stageK = [&](int t) {
#pragma unroll
    for (int i = 0; i < 4; ++i) {
      int c = i*256 + tid; int row = c >> 3, u = c & 7;
      g2l16(kk + (size_t)(bh*TT + t*128 + row)*HD + (u ^ (row & 7))*8,
            smem + (i*256 + w*64)*16);
    }
  };
  auto stageV = [&](int t) {
#pragma unroll
    for (int i = 0; i < 4; ++i) {
      int c = i*256 + tid; int row = c >> 4, u = c & 15;
      g2l16(vt + (size_t)(bh*HD + row)*TT + t*128 + (u ^ (row & 15))*8,
            smem + 16384 + (i*256 + w*64)*16);
    }
  };

  for (int ps = 0; ps < 2; ++ps) {
    int q0 = (ps ? (31 - ip) : ip) * 64;
    int qw = q0 + w * 16;
    int qrow = qw + qi;
    const u16* qbase = q + (size_t)(bh*TT + qrow)*HD + g*8;
    bf8 qf0 = *(const bf8*)(qbase);                        // d 0..31 (8g..8g+7)
    bf8 qf1 = *(const bf8*)(qbase + 32);                   // d 32..63
    float mreg = NEG_INF, lreg = 0.f;
    f4 z = {0.f, 0.f, 0.f, 0.f};
    f4 acc[4]; acc[0] = z; acc[1] = z; acc[2] = z; acc[3] = z;
    int nt = (q0 >> 7) + 1;                                // causal tile count
    stageK(0); stageV(0);                                  // outstanding: 8 instrs
    for (int t = 0; t < nt; ++t) {
      bool last = (t == nt - 1);
      VMCNT4();                                            // K(t) landed (V(t) may fly)
      SBAR();
      __builtin_amdgcn_s_setprio(1);
      f4 sv[8];
#pragma unroll
      for (int jf = 0; jf < 8; ++jf) {                     // Ssw = K Q^T (swapped operands)
        f4 s = z;
        int row = jf*16 + qi;
        int s0 = g ^ (row & 7);
        int s1 = (g + 4) ^ (row & 7);
        bf8 b0 = *(const bf8*)(smem + row*128 + s0*16);
        bf8 b1 = *(const bf8*)(smem + row*128 + s1*16);
        s = __builtin_amdgcn_mfma_f32_16x16x32_bf16(b0, qf0, s, 0, 0, 0);
        s = __builtin_amdgcn_mfma_f32_16x16x32_bf16(b1, qf1, s, 0, 0, 0);
        sv[jf] = s;                                        // key = jf*16+4g+r, q = qi
      }
      __builtin_amdgcn_s_setprio(0);
      LGKMCNT0();                                          // K-buf reads drained
      SBAR();                                              // K-buf free for overwrite
      if (!last) stageK(t + 1);                            // overlap w/ softmax+PV
      if (t*128 + 127 > qw) {                              // diagonal tile: causal mask
        int cbase = qrow - t*128 - 4*g;                    // mask where jf*16+r > cbase
#pragma unroll
        for (int jf = 0; jf < 8; ++jf)
#pragma unroll
          for (int r = 0; r < 4; ++r)
            if (jf*16 + r > cbase) sv[jf][r] = NEG_INF;
      }
      float mx = NEG_INF;                                  // row max: in-lane + cross-g
#pragma unroll
      for (int jf = 0; jf < 8; ++jf)
        mx = fmaxf(mx, fmaxf(fmaxf(sv[jf][0], sv[jf][1]), fmaxf(sv[jf][2], sv[jf][3])));
      mx = fmaxf(mx, __shfl_xor(mx, 16, 64));
      mx = fmaxf(mx, __shfl_xor(mx, 32, 64));
      float mnew = fmaxf(mreg, mx);
      float alpha = exp2fast(mreg - mnew);
      mreg = mnew;
      float rs = 0.f;
#pragma unroll
      for (int jf = 0; jf < 8; ++jf) {                     // P = 2^(S-m), pack -> LDS b64
        float p0 = exp2fast(sv[jf][0] - mreg);
        float p1 = exp2fast(sv[jf][1] - mreg);
        float p2 = exp2fast(sv[jf][2] - mreg);
        float p3 = exp2fast(sv[jf][3] - mreg);
        rs += (p0 + p1) + (p2 + p3);
        uint2 pv;
        pv.x = (u32)f2bf(p0) | ((u32)f2bf(p1) << 16);      // keys jf*16+4g+{0,1}
        pv.y = (u32)f2bf(p2) | ((u32)f2bf(p3) << 16);      // keys jf*16+4g+{2,3}
        int blk = 2*jf + (g >> 1);                         // logical 4-word block
        *(uint2*)(&Pw[qi*68 + 4*((blk + rot2) & 15) + 2*(g & 1)]) = pv;
      }
      rs += __shfl_xor(rs, 16, 64);
      rs += __shfl_xor(rs, 32, 64);
      lreg = lreg * alpha + rs;
#pragma unroll
      for (int df = 0; df < 4; ++df) {                     // rescale O^T accumulator
        f4 a = acc[df];
        a[0] *= alpha; a[1] *= alpha; a[2] *= alpha; a[3] *= alpha;
        acc[df] = a;
      }
      if (!last) { VMCNT4(); } else { VMCNT0(); }          // V(t) landed
      SBAR();
      __builtin_amdgcn_s_setprio(1);
#pragma unroll
      for (int ks = 0; ks < 4; ++ks) {                     // O^T += V^T P^T
        bf8 pf = *(const bf8*)(&Pw[qi*68 + 4*(((4*ks + g) + rot2) & 15)]);
#pragma unroll
        for (int df = 0; df < 4; ++df) {
          int row = df*16 + qi;
          int sl = (ks*4 + g) ^ (row & 15);
          bf8 vf = *(const bf8*)(smem + 16384 + row*256 + sl*16);
          acc[df] = __builtin_amdgcn_mfma_f32_16x16x32_bf16(vf, pf, acc[df], 0, 0, 0);
        }
      }
      __builtin_amdgcn_s_setprio(0);
      LGKMCNT0();                                          // V/P reads drained
      SBAR();                                              // V-buf free for overwrite
      if (!last) stageV(t + 1);                            // overlap w/ next QK^T
    }
    float inv = 1.0f / lreg;                               // epilogue: d = df*16+4g+r
    u16* dst = ctx + (size_t)(b*TT + qrow)*DD + h*HD;
#pragma unroll
    for (int df = 0; df < 4; ++df) {
      uint2 o;
      o.x = (u32)f2bf(acc[df][0] * inv) | ((u32)f2bf(acc[df][1] * inv) << 16);
      o.y = (u32)f2bf(acc[df][2] * inv) | ((u32)f2bf(acc[df][3] * inv) << 16);
      *(uint2*)(dst + df*16 + 4*g) = o;
    }
  }
}

// ---------------- output GEMM: ctx[4096,1024]bf16 @ WoT + bo -> fp32 ----------------
__global__ __launch_bounds__(256, 2) void k_out(const u16* __restrict__ ctx,
    const u16* __restrict__ wot, const float* __restrict__ bo, float* __restrict__ out) {
  __shared__ uint4 smem4[1024];
  char* smem = (char*)smem4;
  int tid = threadIdx.x, w = tid >> 6, l = tid & 63;
  int bid = blockIdx.y * 8 + blockIdx.x;                   // nwg=256
  int wg = (bid & 7) * 32 + (bid >> 3);
  int nb = wg % 8, mb = wg / 8;
  int wm = w >> 1, wn = w & 1;
  f4 z = {0.f, 0.f, 0.f, 0.f};
  f4 acc[4][4];
#pragma unroll
  for (int i = 0; i < 4; ++i)
#pragma unroll
    for (int j = 0; j < 4; ++j) acc[i][j] = z;

  for (int kt = 0; kt < 32; ++kt) {
    int kkk = kt * 32;
    __syncthreads();
#pragma unroll
    for (int i = 0; i < 2; ++i) {
      int c = i*256 + tid; int row = c >> 2, u = c & 3, s = u ^ ((row >> 1) & 3);
      g2l16(ctx + (size_t)(mb*128 + row)*DD + kkk + s*8, smem + (i*256 + w*64)*16);
    }
#pragma unroll
    for (int i = 0; i < 2; ++i) {
      int c = i*256 + tid; int row = c >> 2, u = c & 3, s = u ^ ((row >> 1) & 3);
      g2l16(wot + (size_t)(nb*128 + row)*DD + kkk + s*8, smem + 8192 + (i*256 + w*64)*16);
    }
    __syncthreads();
    bf8 af[4], bfr[4];
#pragma unroll
    for (int mf = 0; mf < 4; ++mf) {
      int row = wm*64 + mf*16 + (l & 15);
      int s = (l >> 4) ^ ((row >> 1) & 3);
      af[mf] = *(const bf8*)(smem + row*64 + s*16);
    }
#pragma unroll
    for (int nf = 0; nf < 4; ++nf) {
      int row = wn*64 + nf*16 + (l & 15);
      int s = (l >> 4) ^ ((row >> 1) & 3);
      bfr[nf] = *(const bf8*)(smem + 8192 + row*64 + s*16);
    }
#pragma unroll
    for (int mf = 0; mf < 4; ++mf)
#pragma unroll
      for (int nf = 0; nf < 4; ++nf)
        acc[mf][nf] = __builtin_amdgcn_mfma_f32_16x16x32_bf16(af[mf], bfr[nf], acc[mf][nf], 0, 0, 0);
  }
#pragma unroll
  for (int nf = 0; nf < 4; ++nf) {
    int n = nb*128 + wn*64 + nf*16 + (l & 15);
    float bias = bo[n];
#pragma unroll
    for (int mf = 0; mf < 4; ++mf) {
      int m0 = mb*128 + wm*64 + mf*16 + (l >> 4)*4;
#pragma unroll
      for (int r = 0; r < 4; ++r)
        out[(size_t)(m0 + r)*DD + n] = acc[mf][nf][r] + bias;
    }
  }
}

extern "C" void kernel_launch(void* const* d_in, const int* in_sizes, int n_in,
                              void* d_out, int out_size, void* d_ws, size_t ws_size,
                              hipStream_t stream) {
  const float* x  = (const float*)d_in[0];
  const float* Wq = (const float*)d_in[1];
  const float* Wk = (const float*)d_in[2];
  const float* Wv = (const float*)d_in[3];
  const float* Wo = (const float*)d_in[4];
  const float* bo = (const float*)d_in[5];
  float* out = (float*)d_out;
  char* ws = (char*)d_ws;

  u16* xb  = (u16*)(ws);                                   // 8 MB bf16 x
  u16* wqt = (u16*)(ws + 8388608);                         // 2 MB each, transposed bf16
  u16* wkt = (u16*)(ws + 10485760);
  u16* wvt = (u16*)(ws + 12582912);
  u16* wot = (u16*)(ws + 14680064);
  u16* qb_ = (u16*)(ws + 16777216);                        // 8 MB [bh][t][64], pre-scaled
  u16* kb_ = (u16*)(ws + 25165824);                        // 8 MB [bh][t][64]
  u16* vtb = (u16*)(ws + 41943040);                        // 8 MB [bh][64][t] (from k_qkv)
  u16* cxb = (u16*)(ws + 50331648);                        // 8 MB [b*t][1024]

  k_cast_x<<<dim3(2048), dim3(256), 0, stream>>>(x, (uint4*)xb);
  k_twcast<<<dim3(16, 16, 4), dim3(256), 0, stream>>>(Wq, Wk, Wv, Wo, wqt, wkt, wvt, wot);
  k_qkv<<<dim3(24, 32), dim3(256), 0, stream>>>(xb, wqt, wkt, wvt, qb_, kb_, vtb);
  k_attn<<<dim3(512), dim3(256), 0, stream>>>(qb_, kb_, vtb, cxb);
  k_out<<<dim3(8, 32), dim3(256), 0, stream>>>(cxb, wot, bo, out);
}

// Round 8
// 174.651 us; speedup vs baseline: 1.3605x; 1.0452x over previous
//
#include <hip/hip_runtime.h>
#include <stdint.h>

typedef unsigned short u16;
typedef unsigned int   u32;
typedef __attribute__((ext_vector_type(8))) __bf16 bf8;   // 8 bf16 = 4 VGPR (MFMA A/B frag)
typedef __attribute__((ext_vector_type(4))) float  f4;    // MFMA C/D frag

#define NEG_INF (-__builtin_inff())

// sizes
#define BB 2
#define TT 2048
#define DD 1024
#define HH 16
#define HD 64
#define BT (BB*TT)   // 4096

#define SBAR() __builtin_amdgcn_s_barrier()
#define VMCNT4() asm volatile("s_waitcnt vmcnt(4)" ::: "memory")
#define VMCNT0() asm volatile("s_waitcnt vmcnt(0)" ::: "memory")
#define LGKMCNT0() asm volatile("s_waitcnt lgkmcnt(0)" ::: "memory")

__device__ __forceinline__ u16 f2bf(float f) {            // RNE fp32->bf16 (inputs finite)
  u32 u = __builtin_bit_cast(u32, f);
  u += 0x7FFFu + ((u >> 16) & 1u);
  return (u16)(u >> 16);
}

__device__ __forceinline__ float exp2fast(float x) {      // native v_exp_f32 (= 2^x)
  float r; asm("v_exp_f32 %0, %1" : "=v"(r) : "v"(x)); return r;
}

__device__ __forceinline__ void g2l16(const void* g, void* l) {
  // async global->LDS, 16B per lane; LDS dest = wave-uniform base + lane*16
  __builtin_amdgcn_global_load_lds((const __attribute__((address_space(1))) u32*)g,
                                   (__attribute__((address_space(3))) u32*)l, 16, 0, 0);
}

// ---------------- cast x: fp32 -> bf16, 8 elems/thread ----------------
__global__ void k_cast_x(const float* __restrict__ x, uint4* __restrict__ xb) {
  int i = blockIdx.x * 256 + threadIdx.x;                  // 524288 threads exactly
  const float4* xf = (const float4*)x;
  float4 a = xf[2*i], b = xf[2*i+1];
  uint4 o;
  o.x = (u32)f2bf(a.x) | ((u32)f2bf(a.y) << 16);
  o.y = (u32)f2bf(a.z) | ((u32)f2bf(a.w) << 16);
  o.z = (u32)f2bf(b.x) | ((u32)f2bf(b.y) << 16);
  o.w = (u32)f2bf(b.z) | ((u32)f2bf(b.w) << 16);
  xb[i] = o;
}

// ------------- transpose+cast weights: W[k][n] f32 -> WT[n][k] bf16 -------------
__global__ void k_twcast(const float* __restrict__ w0, const float* __restrict__ w1,
                         const float* __restrict__ w2, const float* __restrict__ w3,
                         u16* __restrict__ o0, u16* __restrict__ o1,
                         u16* __restrict__ o2, u16* __restrict__ o3) {
  const float* W; u16* O;
  switch (blockIdx.z) {
    case 0: W = w0; O = o0; break;
    case 1: W = w1; O = o1; break;
    case 2: W = w2; O = o2; break;
    default: W = w3; O = o3; break;
  }
  __shared__ __align__(16) u16 tile[64][80];
  int tid = threadIdx.x;
  int k0 = blockIdx.y * 64, n0 = blockIdx.x * 64;
#pragma unroll
  for (int it = 0; it < 4; ++it) {                         // load 64x64 f32, cast
    int c = it*256 + tid; int kr = c >> 4, ns = c & 15;
    float4 v = *(const float4*)(W + (size_t)(k0+kr)*DD + n0 + ns*4);
    u16* p = &tile[kr][ns*4];
    p[0] = f2bf(v.x); p[1] = f2bf(v.y); p[2] = f2bf(v.z); p[3] = f2bf(v.w);
  }
  __syncthreads();
#pragma unroll
  for (int it = 0; it < 2; ++it) {                         // store transposed bf16
    int c = it*256 + tid; int nr = c >> 3, ks = c & 7;
    u32 ww[4];
#pragma unroll
    for (int e = 0; e < 4; ++e) {
      u16 lo = tile[ks*8 + 2*e][nr], hi = tile[ks*8 + 2*e + 1][nr];
      ww[e] = (u32)lo | ((u32)hi << 16);
    }
    uint4 o; o.x = ww[0]; o.y = ww[1]; o.z = ww[2]; o.w = ww[3];
    *(uint4*)(O + (size_t)(n0+nr)*DD + k0 + ks*8) = o;
  }
}

// ---------------- fused QKV GEMM: X[4096,1024]bf16 @ {WqT,WkT,WvT} ----------------
// R8: 2-phase double-buffered pipeline (T3-minimum): stage(t+1) issued BEFORE
// compute(t); one vmcnt(0)+barrier per K-step (no full-drain stall).
// Q written pre-scaled by 0.125*log2e; V written transposed [bh][d][t].
__global__ __launch_bounds__(256, 2) void k_qkv(const u16* __restrict__ xb,
    const u16* __restrict__ wqt, const u16* __restrict__ wkt, const u16* __restrict__ wvt,
    u16* __restrict__ qo, u16* __restrict__ ko, u16* __restrict__ vo) {
  __shared__ __align__(16) char smem[32768];               // [A0 8K|B0 8K][A1 8K|B1 8K]
  int tid = threadIdx.x, w = tid >> 6, l = tid & 63;
  int bid = blockIdx.y * 24 + blockIdx.x;                  // nwg=768, XCD swizzle (768%8==0)
  int wg = (bid & 7) * 96 + (bid >> 3);
  int nb = wg % 24, mb = wg / 24;
  const u16* Bt = (nb < 8) ? wqt : (nb < 16 ? wkt : wvt);
  int nbl = nb & 7;
  int wm = w >> 1, wn = w & 1;
  f4 z = {0.f, 0.f, 0.f, 0.f};
  f4 acc[4][4];
#pragma unroll
  for (int i = 0; i < 4; ++i)
#pragma unroll
    for (int j = 0; j < 4; ++j) acc[i][j] = z;

  auto stage = [&](int buf, int kt) {
    int kk = kt * 32;
    char* dst = smem + buf * 16384;
#pragma unroll
    for (int i = 0; i < 2; ++i) {                          // A tile (swizzled source)
      int c = i*256 + tid; int row = c >> 2, u = c & 3, s = u ^ ((row >> 1) & 3);
      g2l16(xb + (size_t)(mb*128 + row)*DD + kk + s*8, dst + (i*256 + w*64)*16);
    }
#pragma unroll
    for (int i = 0; i < 2; ++i) {                          // B tile
      int c = i*256 + tid; int row = c >> 2, u = c & 3, s = u ^ ((row >> 1) & 3);
      g2l16(Bt + (size_t)(nbl*128 + row)*DD + kk + s*8, dst + 8192 + (i*256 + w*64)*16);
    }
  };

  stage(0, 0);
  VMCNT0(); SBAR();
#pragma unroll 2
  for (int kt = 0; kt < 32; ++kt) {
    int cur = kt & 1;
    if (kt < 31) stage(cur ^ 1, kt + 1);                   // overlap with compute(cur)
    char* buf = smem + cur * 16384;
    bf8 af[4], bfr[4];
#pragma unroll
    for (int mf = 0; mf < 4; ++mf) {
      int row = wm*64 + mf*16 + (l & 15);
      int s = (l >> 4) ^ ((row >> 1) & 3);
      af[mf] = *(const bf8*)(buf + row*64 + s*16);
    }
#pragma unroll
    for (int nf = 0; nf < 4; ++nf) {
      int row = wn*64 + nf*16 + (l & 15);
      int s = (l >> 4) ^ ((row >> 1) & 3);
      bfr[nf] = *(const bf8*)(buf + 8192 + row*64 + s*16);
    }
    __builtin_amdgcn_s_setprio(1);
#pragma unroll
    for (int mf = 0; mf < 4; ++mf)
#pragma unroll
      for (int nf = 0; nf < 4; ++nf)
        acc[mf][nf] = __builtin_amdgcn_mfma_f32_16x16x32_bf16(af[mf], bfr[nf], acc[mf][nf], 0, 0, 0);
    __builtin_amdgcn_s_setprio(0);
    LGKMCNT0();                                            // my LDS reads drained
    VMCNT0(); SBAR();                                      // next buffer ready
  }
  if (nb < 16) {                                           // Q (pre-scaled) or K
    u16* Out = (nb < 8) ? qo : ko;
    float qs = (nb < 8) ? 0.18033688011112042f : 1.0f;     // 0.125*log2(e) for Q
#pragma unroll
    for (int mf = 0; mf < 4; ++mf) {
      int m0 = mb*128 + wm*64 + mf*16 + (l >> 4)*4;
      int b = m0 >> 11;
#pragma unroll
      for (int nf = 0; nf < 4; ++nf) {
        int nn = nbl*128 + wn*64 + nf*16 + (l & 15);
        int h = nn >> 6, d = nn & 63;
#pragma unroll
        for (int r = 0; r < 4; ++r) {
          int t = (m0 + r) & 2047;
          Out[(size_t)((b*HH + h)*TT + t)*HD + d] = f2bf(acc[mf][nf][r] * qs);
        }
      }
    }
  } else {                                                 // V: write transposed [bh][d][t]
#pragma unroll
    for (int mf = 0; mf < 4; ++mf) {
      int m0 = mb*128 + wm*64 + mf*16 + (l >> 4)*4;
      int b = m0 >> 11, t0 = m0 & 2047;
#pragma unroll
      for (int nf = 0; nf < 4; ++nf) {
        int nn = nbl*128 + wn*64 + nf*16 + (l & 15);
        int h = nn >> 6, d = nn & 63;
        uint2 o;
        o.x = (u32)f2bf(acc[mf][nf][0]) | ((u32)f2bf(acc[mf][nf][1]) << 16);
        o.y = (u32)f2bf(acc[mf][nf][2]) | ((u32)f2bf(acc[mf][nf][3]) << 16);
        *(uint2*)(vo + (size_t)((b*HH + h)*HD + d)*TT + t0) = o;
      }
    }
  }
}

// ---------------- flash attention, causal; swapped-QK^T in-register softmax ----------------
// (unchanged from R7; P layout = additive 4-word-block rotation)
__global__ __launch_bounds__(256, 2) void k_attn(const u16* __restrict__ q,
    const u16* __restrict__ kk, const u16* __restrict__ vt, u16* __restrict__ ctx) {
  __shared__ __align__(16) char smem[50176];               // K 16K | V 16K | P 4x4352
  int tid = threadIdx.x, w = tid >> 6, l = tid & 63;
  int qi = l & 15, g = l >> 4;
  int fid = blockIdx.x;
  int xcd = fid & 7, j = fid >> 3;
  int bh  = xcd * 4 + (j & 3);                             // 4 bh per XCD
  int ip  = j >> 2;                                        // 0..15 pair index
  u32* Pw = (u32*)(smem + 32768) + w * 1088;               // per-wave [16 q][68 u32]
  int b = bh >> 4, h = bh & 15;
  int rot2 = 2 * (qi & 7);                                 // additive block rotation

  auto stageK = [&](int t) {
#pragma unroll
    for (int i = 0; i < 4; ++i) {
      int c = i*256 + tid; int row = c >> 3, u = c & 7;
      g2l16(kk + (size_t)(bh*TT + t*128 + row)*HD + (u ^ (row & 7))*8,
            smem + (i*256 + w*64)*16);
    }
  };
  auto stageV = [&](int t) {
#pragma unroll
    for (int i = 0; i < 4; ++i) {
      int c = i*256 + tid; int row = c >> 4, u = c & 15;
      g2l16(vt + (size_t)(bh*HD + row)*TT + t*128 + (u ^ (row & 15))*8,
            smem + 16384 + (i*256 + w*64)*16);
    }
  };

  for (int ps = 0; ps < 2; ++ps) {
    int q0 = (ps ? (31 - ip) : ip) * 64;
    int qw = q0 + w * 16;
    int qrow = qw + qi;
    const u16* qbase = q + (size_t)(bh*TT + qrow)*HD + g*8;
    bf8 qf0 = *(const bf8*)(qbase);                        // d 0..31 (8g..8g+7)
    bf8 qf1 = *(const bf8*)(qbase + 32);                   // d 32..63
    float mreg = NEG_INF, lreg = 0.f;
    f4 z = {0.f, 0.f, 0.f, 0.f};
    f4 acc[4]; acc[0] = z; acc[1] = z; acc[2] = z; acc[3] = z;
    int nt = (q0 >> 7) + 1;                                // causal tile count
    stageK(0); stageV(0);                                  // outstanding: 8 instrs
    for (int t = 0; t < nt; ++t) {
      bool last = (t == nt - 1);
      VMCNT4();                                            // K(t) landed (V(t) may fly)
      SBAR();
      __builtin_amdgcn_s_setprio(1);
      f4 sv[8];
#pragma unroll
      for (int jf = 0; jf < 8; ++jf) {                     // Ssw = K Q^T (swapped operands)
        f4 s = z;
        int row = jf*16 + qi;
        int s0 = g ^ (row & 7);
        int s1 = (g + 4) ^ (row & 7);
        bf8 b0 = *(const bf8*)(smem + row*128 + s0*16);
        bf8 b1 = *(const bf8*)(smem + row*128 + s1*16);
        s = __builtin_amdgcn_mfma_f32_16x16x32_bf16(b0, qf0, s, 0, 0, 0);
        s = __builtin_amdgcn_mfma_f32_16x16x32_bf16(b1, qf1, s, 0, 0, 0);
        sv[jf] = s;                                        // key = jf*16+4g+r, q = qi
      }
      __builtin_amdgcn_s_setprio(0);
      LGKMCNT0();                                          // K-buf reads drained
      SBAR();                                              // K-buf free for overwrite
      if (!last) stageK(t + 1);                            // overlap w/ softmax+PV
      if (t*128 + 127 > qw) {                              // diagonal tile: causal mask
        int cbase = qrow - t*128 - 4*g;                    // mask where jf*16+r > cbase
#pragma unroll
        for (int jf = 0; jf < 8; ++jf)
#pragma unroll
          for (int r = 0; r < 4; ++r)
            if (jf*16 + r > cbase) sv[jf][r] = NEG_INF;
      }
      float mx = NEG_INF;                                  // row max: in-lane + cross-g
#pragma unroll
      for (int jf = 0; jf < 8; ++jf)
        mx = fmaxf(mx, fmaxf(fmaxf(sv[jf][0], sv[jf][1]), fmaxf(sv[jf][2], sv[jf][3])));
      mx = fmaxf(mx, __shfl_xor(mx, 16, 64));
      mx = fmaxf(mx, __shfl_xor(mx, 32, 64));
      float mnew = fmaxf(mreg, mx);
      float alpha = exp2fast(mreg - mnew);
      mreg = mnew;
      float rs = 0.f;
#pragma unroll
      for (int jf = 0; jf < 8; ++jf) {                     // P = 2^(S-m), pack -> LDS b64
        float p0 = exp2fast(sv[jf][0] - mreg);
        float p1 = exp2fast(sv[jf][1] - mreg);
        float p2 = exp2fast(sv[jf][2] - mreg);
        float p3 = exp2fast(sv[jf][3] - mreg);
        rs += (p0 + p1) + (p2 + p3);
        uint2 pv;
        pv.x = (u32)f2bf(p0) | ((u32)f2bf(p1) << 16);      // keys jf*16+4g+{0,1}
        pv.y = (u32)f2bf(p2) | ((u32)f2bf(p3) << 16);      // keys jf*16+4g+{2,3}
        int blk = 2*jf + (g >> 1);                         // logical 4-word block
        *(uint2*)(&Pw[qi*68 + 4*((blk + rot2) & 15) + 2*(g & 1)]) = pv;
      }
      rs += __shfl_xor(rs, 16, 64);
      rs += __shfl_xor(rs, 32, 64);
      lreg = lreg * alpha + rs;
#pragma unroll
      for (int df = 0; df < 4; ++df) {                     // rescale O^T accumulator
        f4 a = acc[df];
        a[0] *= alpha; a[1] *= alpha; a[2] *= alpha; a[3] *= alpha;
        acc[df] = a;
      }
      if (!last) { VMCNT4(); } else { VMCNT0(); }          // V(t) landed
      SBAR();
      __builtin_amdgcn_s_setprio(1);
#pragma unroll
      for (int ks = 0; ks < 4; ++ks) {                     // O^T += V^T P^T
        bf8 pf = *(const bf8*)(&Pw[qi*68 + 4*(((4*ks + g) + rot2) & 15)]);
#pragma unroll
        for (int df = 0; df < 4; ++df) {
          int row = df*16 + qi;
          int sl = (ks*4 + g) ^ (row & 15);
          bf8 vf = *(const bf8*)(smem + 16384 + row*256 + sl*16);
          acc[df] = __builtin_amdgcn_mfma_f32_16x16x32_bf16(vf, pf, acc[df], 0, 0, 0);
        }
      }
      __builtin_amdgcn_s_setprio(0);
      LGKMCNT0();                                          // V/P reads drained
      SBAR();                                              // V-buf free for overwrite
      if (!last) stageV(t + 1);                            // overlap w/ next QK^T
    }
    float inv = 1.0f / lreg;                               // epilogue: d = df*16+4g+r
    u16* dst = ctx + (size_t)(b*TT + qrow)*DD + h*HD;
#pragma unroll
    for (int df = 0; df < 4; ++df) {
      uint2 o;
      o.x = (u32)f2bf(acc[df][0] * inv) | ((u32)f2bf(acc[df][1] * inv) << 16);
      o.y = (u32)f2bf(acc[df][2] * inv) | ((u32)f2bf(acc[df][3] * inv) << 16);
      *(uint2*)(dst + df*16 + 4*g) = o;
    }
  }
}

// ---------------- output GEMM: ctx[4096,1024]bf16 @ WoT + bo -> fp32 ----------------
// R8: 128x64 tile (512 blocks, 2/CU) + 2-phase double-buffered pipeline.
__global__ __launch_bounds__(256, 2) void k_out(const u16* __restrict__ ctx,
    const u16* __restrict__ wot, const float* __restrict__ bo, float* __restrict__ out) {
  __shared__ __align__(16) char smem[24576];               // [A0 8K|B0 4K][A1 8K|B1 4K]
  int tid = threadIdx.x, w = tid >> 6, l = tid & 63;
  int bid = blockIdx.x;                                    // nwg=512, XCD swizzle
  int wg = (bid & 7) * 64 + (bid >> 3);
  int nb = wg % 16, mb = wg / 16;
  int wm = w >> 1, wn = w & 1;
  f4 z = {0.f, 0.f, 0.f, 0.f};
  f4 acc[4][2];
#pragma unroll
  for (int i = 0; i < 4; ++i) { acc[i][0] = z; acc[i][1] = z; }

  auto stage = [&](int buf, int kt) {
    int kk = kt * 32;
    char* dst = smem + buf * 12288;
#pragma unroll
    for (int i = 0; i < 2; ++i) {                          // A tile 128x32
      int c = i*256 + tid; int row = c >> 2, u = c & 3, s = u ^ ((row >> 1) & 3);
      g2l16(ctx + (size_t)(mb*128 + row)*DD + kk + s*8, dst + (i*256 + w*64)*16);
    }
    {                                                      // B tile 64x32 (1 instr)
      int row = tid >> 2, u = tid & 3, s = u ^ ((row >> 1) & 3);
      g2l16(wot + (size_t)(nb*64 + row)*DD + kk + s*8, dst + 8192 + (w*64)*16);
    }
  };

  stage(0, 0);
  VMCNT0(); SBAR();
#pragma unroll 2
  for (int kt = 0; kt < 32; ++kt) {
    int cur = kt & 1;
    if (kt < 31) stage(cur ^ 1, kt + 1);
    char* buf = smem + cur * 12288;
    bf8 af[4], bfr[2];
#pragma unroll
    for (int mf = 0; mf < 4; ++mf) {
      int row = wm*64 + mf*16 + (l & 15);
      int s = (l >> 4) ^ ((row >> 1) & 3);
      af[mf] = *(const bf8*)(buf + row*64 + s*16);
    }
#pragma unroll
    for (int nf = 0; nf < 2; ++nf) {
      int row = wn*32 + nf*16 + (l & 15);
      int s = (l >> 4) ^ ((row >> 1) & 3);
      bfr[nf] = *(const bf8*)(buf + 8192 + row*64 + s*16);
    }
    __builtin_amdgcn_s_setprio(1);
#pragma unroll
    for (int mf = 0; mf < 4; ++mf)
#pragma unroll
      for (int nf = 0; nf < 2; ++nf)
        acc[mf][nf] = __builtin_amdgcn_mfma_f32_16x16x32_bf16(af[mf], bfr[nf], acc[mf][nf], 0, 0, 0);
    __builtin_amdgcn_s_setprio(0);
    LGKMCNT0();
    VMCNT0(); SBAR();
  }
#pragma unroll
  for (int nf = 0; nf < 2; ++nf) {
    int n = nb*64 + wn*32 + nf*16 + (l & 15);
    float bias = bo[n];
#pragma unroll
    for (int mf = 0; mf < 4; ++mf) {
      int m0 = mb*128 + wm*64 + mf*16 + (l >> 4)*4;
#pragma unroll
      for (int r = 0; r < 4; ++r)
        out[(size_t)(m0 + r)*DD + n] = acc[mf][nf][r] + bias;
    }
  }
}

extern "C" void kernel_launch(void* const* d_in, const int* in_sizes, int n_in,
                              void* d_out, int out_size, void* d_ws, size_t ws_size,
                              hipStream_t stream) {
  const float* x  = (const float*)d_in[0];
  const float* Wq = (const float*)d_in[1];
  const float* Wk = (const float*)d_in[2];
  const float* Wv = (const float*)d_in[3];
  const float* Wo = (const float*)d_in[4];
  const float* bo = (const float*)d_in[5];
  float* out = (float*)d_out;
  char* ws = (char*)d_ws;

  u16* xb  = (u16*)(ws);                                   // 8 MB bf16 x
  u16* wqt = (u16*)(ws + 8388608);                         // 2 MB each, transposed bf16
  u16* wkt = (u16*)(ws + 10485760);
  u16* wvt = (u16*)(ws + 12582912);
  u16* wot = (u16*)(ws + 14680064);
  u16* qb_ = (u16*)(ws + 16777216);                        // 8 MB [bh][t][64], pre-scaled
  u16* kb_ = (u16*)(ws + 25165824);                        // 8 MB [bh][t][64]
  u16* vtb = (u16*)(ws + 41943040);                        // 8 MB [bh][64][t] (from k_qkv)
  u16* cxb = (u16*)(ws + 50331648);                        // 8 MB [b*t][1024]

  k_cast_x<<<dim3(2048), dim3(256), 0, stream>>>(x, (uint4*)xb);
  k_twcast<<<dim3(16, 16, 4), dim3(256), 0, stream>>>(Wq, Wk, Wv, Wo, wqt, wkt, wvt, wot);
  k_qkv<<<dim3(24, 32), dim3(256), 0, stream>>>(xb, wqt, wkt, wvt, qb_, kb_, vtb);
  k_attn<<<dim3(512), dim3(256), 0, stream>>>(qb_, kb_, vtb, cxb);
  k_out<<<dim3(512), dim3(256), 0, stream>>>(cxb, wot, bo, out);
}

// Round 9
// 166.583 us; speedup vs baseline: 1.4264x; 1.0484x over previous
//
#include <hip/hip_runtime.h>
#include <stdint.h>

typedef unsigned short u16;
typedef unsigned int   u32;
typedef __attribute__((ext_vector_type(8))) __bf16 bf8;   // 8 bf16 = 4 VGPR (MFMA A/B frag)
typedef __attribute__((ext_vector_type(2))) __bf16 bf2;
typedef __attribute__((ext_vector_type(4))) float  f4;    // MFMA C/D frag

#define NEG_INF (-__builtin_inff())

// sizes
#define BB 2
#define TT 2048
#define DD 1024
#define HH 16
#define HD 64
#define BT (BB*TT)   // 4096

#define SBAR() __builtin_amdgcn_s_barrier()
#define VMCNT4() asm volatile("s_waitcnt vmcnt(4)" ::: "memory")
#define VMCNT0() asm volatile("s_waitcnt vmcnt(0)" ::: "memory")
#define LGKMCNT0() asm volatile("s_waitcnt lgkmcnt(0)" ::: "memory")

__device__ __forceinline__ u16 f2bf(float f) {            // RNE fp32->bf16 (inputs finite)
  u32 u = __builtin_bit_cast(u32, f);
  u += 0x7FFFu + ((u >> 16) & 1u);
  return (u16)(u >> 16);
}

__device__ __forceinline__ u32 pkbf(float a, float b) {   // native cvt pair -> u32
  bf2 v; v[0] = (__bf16)a; v[1] = (__bf16)b;
  return __builtin_bit_cast(u32, v);
}

__device__ __forceinline__ float exp2fast(float x) {      // native v_exp_f32 (= 2^x)
  float r; asm("v_exp_f32 %0, %1" : "=v"(r) : "v"(x)); return r;
}

__device__ __forceinline__ void g2l16(const void* g, void* l) {
  // async global->LDS, 16B per lane; LDS dest = wave-uniform base + lane*16
  __builtin_amdgcn_global_load_lds((const __attribute__((address_space(1))) u32*)g,
                                   (__attribute__((address_space(3))) u32*)l, 16, 0, 0);
}

// ---------------- cast x: fp32 -> bf16, 8 elems/thread ----------------
__global__ void k_cast_x(const float* __restrict__ x, uint4* __restrict__ xb) {
  int i = blockIdx.x * 256 + threadIdx.x;                  // 524288 threads exactly
  const float4* xf = (const float4*)x;
  float4 a = xf[2*i], b = xf[2*i+1];
  uint4 o;
  o.x = (u32)f2bf(a.x) | ((u32)f2bf(a.y) << 16);
  o.y = (u32)f2bf(a.z) | ((u32)f2bf(a.w) << 16);
  o.z = (u32)f2bf(b.x) | ((u32)f2bf(b.y) << 16);
  o.w = (u32)f2bf(b.z) | ((u32)f2bf(b.w) << 16);
  xb[i] = o;
}

// ------------- transpose+cast weights: W[k][n] f32 -> WT[n][k] bf16 -------------
__global__ void k_twcast(const float* __restrict__ w0, const float* __restrict__ w1,
                         const float* __restrict__ w2, const float* __restrict__ w3,
                         u16* __restrict__ o0, u16* __restrict__ o1,
                         u16* __restrict__ o2, u16* __restrict__ o3) {
  const float* W; u16* O;
  switch (blockIdx.z) {
    case 0: W = w0; O = o0; break;
    case 1: W = w1; O = o1; break;
    case 2: W = w2; O = o2; break;
    default: W = w3; O = o3; break;
  }
  __shared__ __align__(16) u16 tile[64][80];
  int tid = threadIdx.x;
  int k0 = blockIdx.y * 64, n0 = blockIdx.x * 64;
#pragma unroll
  for (int it = 0; it < 4; ++it) {                         // load 64x64 f32, cast
    int c = it*256 + tid; int kr = c >> 4, ns = c & 15;
    float4 v = *(const float4*)(W + (size_t)(k0+kr)*DD + n0 + ns*4);
    u16* p = &tile[kr][ns*4];
    p[0] = f2bf(v.x); p[1] = f2bf(v.y); p[2] = f2bf(v.z); p[3] = f2bf(v.w);
  }
  __syncthreads();
#pragma unroll
  for (int it = 0; it < 2; ++it) {                         // store transposed bf16
    int c = it*256 + tid; int nr = c >> 3, ks = c & 7;
    u32 ww[4];
#pragma unroll
    for (int e = 0; e < 4; ++e) {
      u16 lo = tile[ks*8 + 2*e][nr], hi = tile[ks*8 + 2*e + 1][nr];
      ww[e] = (u32)lo | ((u32)hi << 16);
    }
    uint4 o; o.x = ww[0]; o.y = ww[1]; o.z = ww[2]; o.w = ww[3];
    *(uint4*)(O + (size_t)(n0+nr)*DD + k0 + ks*8) = o;
  }
}

// ---------------- fused QKV GEMM: X[4096,1024]bf16 @ {WqT,WkT,WvT} ----------------
// R9: BK=64 (16 K-steps, 32 MFMA/step between barriers), 2-phase dbuf pipeline.
// LDS tile [128 rows][8 chunks of 16B], chunk swizzle ch ^= row&7 (2-way = free).
// Q pre-scaled by 0.125*log2e; V written transposed [bh][d][t].
__global__ __launch_bounds__(256, 2) void k_qkv(const u16* __restrict__ xb,
    const u16* __restrict__ wqt, const u16* __restrict__ wkt, const u16* __restrict__ wvt,
    u16* __restrict__ qo, u16* __restrict__ ko, u16* __restrict__ vo) {
  __shared__ __align__(16) char smem[65536];               // 2 x (A 16K | B 16K)
  int tid = threadIdx.x, w = tid >> 6, l = tid & 63;
  int bid = blockIdx.y * 24 + blockIdx.x;                  // nwg=768, XCD swizzle (768%8==0)
  int wg = (bid & 7) * 96 + (bid >> 3);
  int nb = wg % 24, mb = wg / 24;
  const u16* Bt = (nb < 8) ? wqt : (nb < 16 ? wkt : wvt);
  int nbl = nb & 7;
  int wm = w >> 1, wn = w & 1;
  int qi = l & 15, g = l >> 4;
  f4 z = {0.f, 0.f, 0.f, 0.f};
  f4 acc[4][4];
#pragma unroll
  for (int i = 0; i < 4; ++i)
#pragma unroll
    for (int j = 0; j < 4; ++j) acc[i][j] = z;

  auto stage = [&](int buf, int kt) {                      // 8 g2l16, 32 KB
    int kk = kt * 64;
    char* dst = smem + buf * 32768;
#pragma unroll
    for (int i = 0; i < 4; ++i) {                          // A 128x64
      int c = i*256 + tid; int row = c >> 3, u = c & 7, s = u ^ (row & 7);
      g2l16(xb + (size_t)(mb*128 + row)*DD + kk + s*8, dst + (i*256 + w*64)*16);
    }
#pragma unroll
    for (int i = 0; i < 4; ++i) {                          // B 128x64
      int c = i*256 + tid; int row = c >> 3, u = c & 7, s = u ^ (row & 7);
      g2l16(Bt + (size_t)(nbl*128 + row)*DD + kk + s*8, dst + 16384 + (i*256 + w*64)*16);
    }
  };

  stage(0, 0);
  VMCNT0(); SBAR();
#pragma unroll 2
  for (int kt = 0; kt < 16; ++kt) {
    int cur = kt & 1;
    if (kt < 15) stage(cur ^ 1, kt + 1);                   // overlap with compute(cur)
    char* buf = smem + cur * 32768;
#pragma unroll
    for (int ks2 = 0; ks2 < 2; ++ks2) {                    // two K=32 sub-steps
      bf8 af[4], bfr[4];
#pragma unroll
      for (int mf = 0; mf < 4; ++mf) {
        int row = wm*64 + mf*16 + qi;
        int s = (ks2*4 + g) ^ (row & 7);
        af[mf] = *(const bf8*)(buf + row*128 + s*16);
      }
#pragma unroll
      for (int nf = 0; nf < 4; ++nf) {
        int row = wn*64 + nf*16 + qi;
        int s = (ks2*4 + g) ^ (row & 7);
        bfr[nf] = *(const bf8*)(buf + 16384 + row*128 + s*16);
      }
      __builtin_amdgcn_s_setprio(1);
#pragma unroll
      for (int mf = 0; mf < 4; ++mf)
#pragma unroll
        for (int nf = 0; nf < 4; ++nf)
          acc[mf][nf] = __builtin_amdgcn_mfma_f32_16x16x32_bf16(af[mf], bfr[nf], acc[mf][nf], 0, 0, 0);
      __builtin_amdgcn_s_setprio(0);
    }
    LGKMCNT0();                                            // my LDS reads drained
    VMCNT0(); SBAR();                                      // next buffer ready
  }
  if (nb < 16) {                                           // Q (pre-scaled) or K
    u16* Out = (nb < 8) ? qo : ko;
    float qs = (nb < 8) ? 0.18033688011112042f : 1.0f;     // 0.125*log2(e) for Q
#pragma unroll
    for (int mf = 0; mf < 4; ++mf) {
      int m0 = mb*128 + wm*64 + mf*16 + g*4;
      int b = m0 >> 11;
#pragma unroll
      for (int nf = 0; nf < 4; ++nf) {
        int nn = nbl*128 + wn*64 + nf*16 + qi;
        int h = nn >> 6, d = nn & 63;
#pragma unroll
        for (int r = 0; r < 4; ++r) {
          int t = (m0 + r) & 2047;
          Out[(size_t)((b*HH + h)*TT + t)*HD + d] = f2bf(acc[mf][nf][r] * qs);
        }
      }
    }
  } else {                                                 // V: write transposed [bh][d][t]
#pragma unroll
    for (int mf = 0; mf < 4; ++mf) {
      int m0 = mb*128 + wm*64 + mf*16 + g*4;
      int b = m0 >> 11, t0 = m0 & 2047;
#pragma unroll
      for (int nf = 0; nf < 4; ++nf) {
        int nn = nbl*128 + wn*64 + nf*16 + qi;
        int h = nn >> 6, d = nn & 63;
        uint2 o;
        o.x = (u32)f2bf(acc[mf][nf][0]) | ((u32)f2bf(acc[mf][nf][1]) << 16);
        o.y = (u32)f2bf(acc[mf][nf][2]) | ((u32)f2bf(acc[mf][nf][3]) << 16);
        *(uint2*)(vo + (size_t)((b*HH + h)*HD + d)*TT + t0) = o;
      }
    }
  }
}

// ---------------- flash attention, causal; swapped-QK^T in-register softmax ----------------
// R9: native bf16 cvt for P-pack (saves ~80 VALU/iter); defer-max THR=8 (T13).
// P LDS: per-wave [16 q][68 u32], additive 4-word-block rotation (R7).
__global__ __launch_bounds__(256, 2) void k_attn(const u16* __restrict__ q,
    const u16* __restrict__ kk, const u16* __restrict__ vt, u16* __restrict__ ctx) {
  __shared__ __align__(16) char smem[50176];               // K 16K | V 16K | P 4x4352
  int tid = threadIdx.x, w = tid >> 6, l = tid & 63;
  int qi = l & 15, g = l >> 4;
  int fid = blockIdx.x;
  int xcd = fid & 7, j = fid >> 3;
  int bh  = xcd * 4 + (j & 3);                             // 4 bh per XCD
  int ip  = j >> 2;                                        // 0..15 pair index
  u32* Pw = (u32*)(smem + 32768) + w * 1088;               // per-wave [16 q][68 u32]
  int b = bh >> 4, h = bh & 15;
  int rot2 = 2 * (qi & 7);                                 // additive block rotation

  auto stageK = [&](int t) {
#pragma unroll
    for (int i = 0; i < 4; ++i) {
      int c = i*256 + tid; int row = c >> 3, u = c & 7;
      g2l16(kk + (size_t)(bh*TT + t*128 + row)*HD + (u ^ (row & 7))*8,
            smem + (i*256 + w*64)*16);
    }
  };
  auto stageV = [&](int t) {
#pragma unroll
    for (int i = 0; i < 4; ++i) {
      int c = i*256 + tid; int row = c >> 4, u = c & 15;
      g2l16(vt + (size_t)(bh*HD + row)*TT + t*128 + (u ^ (row & 15))*8,
            smem + 16384 + (i*256 + w*64)*16);
    }
  };

  for (int ps = 0; ps < 2; ++ps) {
    int q0 = (ps ? (31 - ip) : ip) * 64;
    int qw = q0 + w * 16;
    int qrow = qw + qi;
    const u16* qbase = q + (size_t)(bh*TT + qrow)*HD + g*8;
    bf8 qf0 = *(const bf8*)(qbase);                        // d 0..31 (8g..8g+7)
    bf8 qf1 = *(const bf8*)(qbase + 32);                   // d 32..63
    float mreg = NEG_INF, lreg = 0.f;
    f4 z = {0.f, 0.f, 0.f, 0.f};
    f4 acc[4]; acc[0] = z; acc[1] = z; acc[2] = z; acc[3] = z;
    int nt = (q0 >> 7) + 1;                                // causal tile count
    stageK(0); stageV(0);                                  // outstanding: 8 instrs
    for (int t = 0; t < nt; ++t) {
      bool last = (t == nt - 1);
      VMCNT4();                                            // K(t) landed (V(t) may fly)
      SBAR();
      __builtin_amdgcn_s_setprio(1);
      f4 sv[8];
#pragma unroll
      for (int jf = 0; jf < 8; ++jf) {                     // Ssw = K Q^T (swapped operands)
        f4 s = z;
        int row = jf*16 + qi;
        int s0 = g ^ (row & 7);
        int s1 = (g + 4) ^ (row & 7);
        bf8 b0 = *(const bf8*)(smem + row*128 + s0*16);
        bf8 b1 = *(const bf8*)(smem + row*128 + s1*16);
        s = __builtin_amdgcn_mfma_f32_16x16x32_bf16(b0, qf0, s, 0, 0, 0);
        s = __builtin_amdgcn_mfma_f32_16x16x32_bf16(b1, qf1, s, 0, 0, 0);
        sv[jf] = s;                                        // key = jf*16+4g+r, q = qi
      }
      __builtin_amdgcn_s_setprio(0);
      LGKMCNT0();                                          // K-buf reads drained
      SBAR();                                              // K-buf free for overwrite
      if (!last) stageK(t + 1);                            // overlap w/ softmax+PV
      if (t*128 + 127 > qw) {                              // diagonal tile: causal mask
        int cbase = qrow - t*128 - 4*g;                    // mask where jf*16+r > cbase
#pragma unroll
        for (int jf = 0; jf < 8; ++jf)
#pragma unroll
          for (int r = 0; r < 4; ++r)
            if (jf*16 + r > cbase) sv[jf][r] = NEG_INF;
      }
      float mx = NEG_INF;                                  // row max: in-lane + cross-g
#pragma unroll
      for (int jf = 0; jf < 8; ++jf)
        mx = fmaxf(mx, fmaxf(fmaxf(sv[jf][0], sv[jf][1]), fmaxf(sv[jf][2], sv[jf][3])));
      mx = fmaxf(mx, __shfl_xor(mx, 16, 64));
      mx = fmaxf(mx, __shfl_xor(mx, 32, 64));
      if (!__all(mx <= mreg + 8.f)) {                      // defer-max (T13): P <= 2^8
        float mnew = fmaxf(mreg, mx);
        float alpha = exp2fast(mreg - mnew);
        mreg = mnew;
        lreg *= alpha;
#pragma unroll
        for (int df = 0; df < 4; ++df) {                   // rescale O^T accumulator
          f4 a = acc[df];
          a[0] *= alpha; a[1] *= alpha; a[2] *= alpha; a[3] *= alpha;
          acc[df] = a;
        }
      }
      float rs = 0.f;
#pragma unroll
      for (int jf = 0; jf < 8; ++jf) {                     // P = 2^(S-m), pack -> LDS b64
        float p0 = exp2fast(sv[jf][0] - mreg);
        float p1 = exp2fast(sv[jf][1] - mreg);
        float p2 = exp2fast(sv[jf][2] - mreg);
        float p3 = exp2fast(sv[jf][3] - mreg);
        rs += (p0 + p1) + (p2 + p3);
        uint2 pv;
        pv.x = pkbf(p0, p1);                               // keys jf*16+4g+{0,1}
        pv.y = pkbf(p2, p3);                               // keys jf*16+4g+{2,3}
        int blk = 2*jf + (g >> 1);                         // logical 4-word block
        *(uint2*)(&Pw[qi*68 + 4*((blk + rot2) & 15) + 2*(g & 1)]) = pv;
      }
      rs += __shfl_xor(rs, 16, 64);
      rs += __shfl_xor(rs, 32, 64);
      lreg += rs;
      if (!last) { VMCNT4(); } else { VMCNT0(); }          // V(t) landed
      SBAR();
      __builtin_amdgcn_s_setprio(1);
#pragma unroll
      for (int ks = 0; ks < 4; ++ks) {                     // O^T += V^T P^T
        bf8 pf = *(const bf8*)(&Pw[qi*68 + 4*(((4*ks + g) + rot2) & 15)]);
#pragma unroll
        for (int df = 0; df < 4; ++df) {
          int row = df*16 + qi;
          int sl = (ks*4 + g) ^ (row & 15);
          bf8 vf = *(const bf8*)(smem + 16384 + row*256 + sl*16);
          acc[df] = __builtin_amdgcn_mfma_f32_16x16x32_bf16(vf, pf, acc[df], 0, 0, 0);
        }
      }
      __builtin_amdgcn_s_setprio(0);
      LGKMCNT0();                                          // V/P reads drained
      SBAR();                                              // V-buf free for overwrite
      if (!last) stageV(t + 1);                            // overlap w/ next QK^T
    }
    float inv = 1.0f / lreg;                               // epilogue: d = df*16+4g+r
    u16* dst = ctx + (size_t)(b*TT + qrow)*DD + h*HD;
#pragma unroll
    for (int df = 0; df < 4; ++df) {
      uint2 o;
      o.x = pkbf(acc[df][0] * inv, acc[df][1] * inv);
      o.y = pkbf(acc[df][2] * inv, acc[df][3] * inv);
      *(uint2*)(dst + df*16 + 4*g) = o;
    }
  }
}

// ---------------- output GEMM: ctx[4096,1024]bf16 @ WoT + bo -> fp32 ----------------
// R9: 128x64 tile, BK=64 (16 K-steps), 2-phase dbuf pipeline.
__global__ __launch_bounds__(256, 2) void k_out(const u16* __restrict__ ctx,
    const u16* __restrict__ wot, const float* __restrict__ bo, float* __restrict__ out) {
  __shared__ __align__(16) char smem[49152];               // 2 x (A 16K | B 8K)
  int tid = threadIdx.x, w = tid >> 6, l = tid & 63;
  int bid = blockIdx.x;                                    // nwg=512, XCD swizzle
  int wg = (bid & 7) * 64 + (bid >> 3);
  int nb = wg % 16, mb = wg / 16;
  int wm = w >> 1, wn = w & 1;
  int qi = l & 15, g = l >> 4;
  f4 z = {0.f, 0.f, 0.f, 0.f};
  f4 acc[4][2];
#pragma unroll
  for (int i = 0; i < 4; ++i) { acc[i][0] = z; acc[i][1] = z; }

  auto stage = [&](int buf, int kt) {                      // 6 g2l16, 24 KB
    int kk = kt * 64;
    char* dst = smem + buf * 24576;
#pragma unroll
    for (int i = 0; i < 4; ++i) {                          // A 128x64
      int c = i*256 + tid; int row = c >> 3, u = c & 7, s = u ^ (row & 7);
      g2l16(ctx + (size_t)(mb*128 + row)*DD + kk + s*8, dst + (i*256 + w*64)*16);
    }
#pragma unroll
    for (int i = 0; i < 2; ++i) {                          // B 64x64
      int c = i*256 + tid; int row = c >> 3, u = c & 7, s = u ^ (row & 7);
      g2l16(wot + (size_t)(nb*64 + row)*DD + kk + s*8, dst + 16384 + (i*256 + w*64)*16);
    }
  };

  stage(0, 0);
  VMCNT0(); SBAR();
#pragma unroll 2
  for (int kt = 0; kt < 16; ++kt) {
    int cur = kt & 1;
    if (kt < 15) stage(cur ^ 1, kt + 1);
    char* buf = smem + cur * 24576;
#pragma unroll
    for (int ks2 = 0; ks2 < 2; ++ks2) {
      bf8 af[4], bfr[2];
#pragma unroll
      for (int mf = 0; mf < 4; ++mf) {
        int row = wm*64 + mf*16 + qi;
        int s = (ks2*4 + g) ^ (row & 7);
        af[mf] = *(const bf8*)(buf + row*128 + s*16);
      }
#pragma unroll
      for (int nf = 0; nf < 2; ++nf) {
        int row = wn*32 + nf*16 + qi;
        int s = (ks2*4 + g) ^ (row & 7);
        bfr[nf] = *(const bf8*)(buf + 16384 + row*128 + s*16);
      }
      __builtin_amdgcn_s_setprio(1);
#pragma unroll
      for (int mf = 0; mf < 4; ++mf)
#pragma unroll
        for (int nf = 0; nf < 2; ++nf)
          acc[mf][nf] = __builtin_amdgcn_mfma_f32_16x16x32_bf16(af[mf], bfr[nf], acc[mf][nf], 0, 0, 0);
      __builtin_amdgcn_s_setprio(0);
    }
    LGKMCNT0();
    VMCNT0(); SBAR();
  }
#pragma unroll
  for (int nf = 0; nf < 2; ++nf) {
    int n = nb*64 + wn*32 + nf*16 + qi;
    float bias = bo[n];
#pragma unroll
    for (int mf = 0; mf < 4; ++mf) {
      int m0 = mb*128 + wm*64 + mf*16 + g*4;
#pragma unroll
      for (int r = 0; r < 4; ++r)
        out[(size_t)(m0 + r)*DD + n] = acc[mf][nf][r] + bias;
    }
  }
}

extern "C" void kernel_launch(void* const* d_in, const int* in_sizes, int n_in,
                              void* d_out, int out_size, void* d_ws, size_t ws_size,
                              hipStream_t stream) {
  const float* x  = (const float*)d_in[0];
  const float* Wq = (const float*)d_in[1];
  const float* Wk = (const float*)d_in[2];
  const float* Wv = (const float*)d_in[3];
  const float* Wo = (const float*)d_in[4];
  const float* bo = (const float*)d_in[5];
  float* out = (float*)d_out;
  char* ws = (char*)d_ws;

  u16* xb  = (u16*)(ws);                                   // 8 MB bf16 x
  u16* wqt = (u16*)(ws + 8388608);                         // 2 MB each, transposed bf16
  u16* wkt = (u16*)(ws + 10485760);
  u16* wvt = (u16*)(ws + 12582912);
  u16* wot = (u16*)(ws + 14680064);
  u16* qb_ = (u16*)(ws + 16777216);                        // 8 MB [bh][t][64], pre-scaled
  u16* kb_ = (u16*)(ws + 25165824);                        // 8 MB [bh][t][64]
  u16* vtb = (u16*)(ws + 41943040);                        // 8 MB [bh][64][t] (from k_qkv)
  u16* cxb = (u16*)(ws + 50331648);                        // 8 MB [b*t][1024]

  k_cast_x<<<dim3(2048), dim3(256), 0, stream>>>(x, (uint4*)xb);
  k_twcast<<<dim3(16, 16, 4), dim3(256), 0, stream>>>(Wq, Wk, Wv, Wo, wqt, wkt, wvt, wot);
  k_qkv<<<dim3(24, 32), dim3(256), 0, stream>>>(xb, wqt, wkt, wvt, qb_, kb_, vtb);
  k_attn<<<dim3(512), dim3(256), 0, stream>>>(qb_, kb_, vtb, cxb);
  k_out<<<dim3(512), dim3(256), 0, stream>>>(cxb, wot, bo, out);
}